// Round 5
// baseline (422.024 us; speedup 1.0000x reference)
//
#include <hip/hip_runtime.h>
#include <hip/hip_bf16.h>

// ---- problem constants ----
constexpr int NN = 16000, NE = 48000, NF = 32000;
constexpr int ND = 64, NB = 32, NG = 32;
constexpr int HIDN = 256, NCLS = 10;
constexpr int QG = 8, CHUNKS = 32;            // 8 graphs/round, 32 chunk-blocks/graph
constexpr float KLOG = 144.26950408889634f;   // 100 * log2(e)
constexpr float DLT  = 9.307710457348151f;    // (2/31) * KLOG

// ---- ws word layout ----
constexpr int ECCP_OFF = 0;                   // [16384] f32 round partials (64 KB)
constexpr int C32_OFF  = 16384;               // [64]  u32 hist (e:0..31, f:32..63)
constexpr int O32_OFF  = 16448;               // [66]  i32 offsets (e:0..32, f:33..65)
constexpr int CUR_OFF  = 16514;               // [16]  u32 round cursors
constexpr int ZERO_WORDS = 16530;             // zero ECCP+C32+O32+CUR
constexpr int NOFS_OFF = 16530;               // [33]  i32 node boundaries
constexpr int FLG_OFF  = 16563;               // [2]   u32 {fp_is_bf16, int_is_64}
constexpr int PERM_OFF = 16566;               // u16 perm_e/perm_f tail (host-sized)

__device__ __forceinline__ int clamp_node(int n) {
    return ((unsigned)n < (unsigned)NN) ? n : 0;
}
template<bool BF> __device__ __forceinline__ float ldf(const void* p, int i) {
    return BF ? __bfloat162float(((const __hip_bfloat16*)p)[i]) : ((const float*)p)[i];
}
template<bool I64> __device__ __forceinline__ int ldi(const int* p, int i) {
    return I64 ? p[2 * i] : p[i];
}

// D: dtype detection (1 block). flags[0]=floats-are-bf16, flags[1]=ints-are-64bit
__global__ __launch_bounds__(256) void k_detect(const unsigned* __restrict__ xw,
                                                const unsigned* __restrict__ eiw,
                                                unsigned* __restrict__ flags) {
    __shared__ unsigned sb[2];
    int t = threadIdx.x;
    if (t < 2) sb[t] = 0;
    __syncthreads();
    unsigned w = xw[t];                        // first 256 words of x (safe both widths)
    if (((w >> 23) & 0xFFu) >= 200u) atomicOr(&sb[0], 1u);   // bf16-pair signature
    unsigned o = eiw[2 * t + 1];               // odd words of edge_index
    if (o != 0u) atomicOr(&sb[1], 1u);         // nonzero odd word => int32
    __syncthreads();
    if (t == 0) { flags[0] = sb[0]; flags[1] = 1u - sb[1]; }
}

// K0: zero head + node range boundaries from sorted batch_ids
template<bool I64>
__device__ __forceinline__ void init_body(const int* batch, float* wsf, int* wsi) {
    int gid = blockIdx.x * 256 + threadIdx.x;
    if (gid < ZERO_WORDS) wsf[gid] = 0.0f;
    if (gid < NN) {
        int gn = ldi<I64>(batch, gid) & (NG - 1);
        int gp = (gid > 0) ? (ldi<I64>(batch, gid - 1) & (NG - 1)) : -1;
        for (int gg = gp + 1; gg <= gn; gg++) wsi[NOFS_OFF + gg] = gid;
        if (gid == NN - 1)
            for (int gg = gn + 1; gg <= NG; gg++) wsi[NOFS_OFF + gg] = NN;
    }
}
__global__ __launch_bounds__(256) void k_init(const int* __restrict__ batch,
                                              float* __restrict__ wsf,
                                              int* __restrict__ wsi,
                                              const unsigned* __restrict__ flags) {
    if (flags[1]) init_body<true>(batch, wsf, wsi);
    else         init_body<false>(batch, wsf, wsi);
}

// K1: 32-bin histograms for edges and faces
template<bool I64>
__device__ __forceinline__ void hist_body(const int* ei, const int* fc, const int* batch,
                                          unsigned* wsu) {
    __shared__ unsigned hb[64];
    int t = threadIdx.x;
    if (t < 64) hb[t] = 0;
    __syncthreads();
    int id = blockIdx.x * 256 + t;
    if (id < NE + NF) {
        if (id < NE) atomicAdd(&hb[ldi<I64>(batch, clamp_node(ldi<I64>(ei, id))) & 31], 1u);
        else         atomicAdd(&hb[32 + (ldi<I64>(batch, clamp_node(ldi<I64>(fc, id - NE))) & 31)], 1u);
    }
    __syncthreads();
    if (t < 64 && hb[t]) atomicAdd(&wsu[C32_OFF + t], hb[t]);
}
__global__ __launch_bounds__(256) void k_hist32(const int* __restrict__ ei,
                                                const int* __restrict__ fc,
                                                const int* __restrict__ batch,
                                                unsigned* __restrict__ wsu,
                                                const unsigned* __restrict__ flags) {
    if (flags[1]) hist_body<true>(ei, fc, batch, wsu);
    else         hist_body<false>(ei, fc, batch, wsu);
}

// K2: exclusive prefix for both histograms
__global__ void k_prefix32(const unsigned* __restrict__ wsu, int* __restrict__ wsi) {
    if (threadIdx.x == 0) {
        int acc = 0;
        for (int i = 0; i < NG; i++) { wsi[O32_OFF + i] = acc; acc += (int)wsu[C32_OFF + i]; }
        wsi[O32_OFF + NG] = acc;
        acc = 0;
        for (int i = 0; i < NG; i++) { wsi[O32_OFF + 33 + i] = acc; acc += (int)wsu[C32_OFF + 32 + i]; }
        wsi[O32_OFF + 33 + NG] = acc;
    }
}

// K3: scatter round-q edges/faces into u16 buckets (bounds-checked)
template<bool I64>
__device__ __forceinline__ void scatter_body(int q, const int* ei, const int* fc,
                                             const int* batch, const int* wsi,
                                             unsigned* wsu,
                                             unsigned short* pe, int cap_e,
                                             unsigned short* pf, int cap_f) {
    __shared__ unsigned cnt[16];
    __shared__ unsigned base[16];
    int t = threadIdx.x;
    if (t < 16) cnt[t] = 0;
    __syncthreads();
    int id = blockIdx.x * 256 + t;
    int bin = 0; unsigned rank = 0; bool active = false; bool isf = false;
    if (id < NE + NF) {
        int g;
        if (id < NE) g = ldi<I64>(batch, clamp_node(ldi<I64>(ei, id))) & 31;
        else       { g = ldi<I64>(batch, clamp_node(ldi<I64>(fc, id - NE))) & 31; isf = true; }
        if ((g >> 3) == q) {
            active = true;
            bin = (g & 7) + (isf ? 8 : 0);
            rank = atomicAdd(&cnt[bin], 1u);
        }
    }
    __syncthreads();
    if (t < 16) base[t] = cnt[t] ? atomicAdd(&wsu[CUR_OFF + t], cnt[t]) : 0u;
    __syncthreads();
    if (active) {
        int gq = bin & 7;
        if (!isf) {
            int pos = (wsi[O32_OFF + q*QG + gq] - wsi[O32_OFF + q*QG]) + (int)(base[bin] + rank);
            if (pos >= 0 && pos < cap_e) pe[pos] = (unsigned short)id;
        } else {
            int pos = (wsi[O32_OFF + 33 + q*QG + gq] - wsi[O32_OFF + 33 + q*QG]) + (int)(base[bin] + rank);
            if (pos >= 0 && pos < cap_f) pf[pos] = (unsigned short)(id - NE);
        }
    }
}
__global__ __launch_bounds__(256) void k_scatter(int q, const int* __restrict__ ei,
                                                 const int* __restrict__ fc,
                                                 const int* __restrict__ batch,
                                                 const int* __restrict__ wsi,
                                                 unsigned* __restrict__ wsu,
                                                 unsigned short* __restrict__ pe, int cap_e,
                                                 unsigned short* __restrict__ pf, int cap_f,
                                                 const unsigned* __restrict__ flags) {
    if (flags[1]) scatter_body<true>(q, ei, fc, batch, wsi, wsu, pe, cap_e, pf, cap_f);
    else         scatter_body<false>(q, ei, fc, batch, wsi, wsu, pe, cap_e, pf, cap_f);
}

// sigmoid ladder: one exp2 per element, 7 chained scalings
__device__ __forceinline__ void accum8(float h, float s, float linc0, float kdec,
                                       float* acc) {
    float t0 = fminf(fmaxf(h * KLOG - linc0, -60.0f), 126.0f);
    float e2 = __builtin_amdgcn_exp2f(t0);
#pragma unroll
    for (int j = 0; j < 8; j++) {
        acc[j] = fmaf(s, __builtin_amdgcn_rcpf(1.0f + e2), acc[j]);
        e2 *= kdec;
    }
}

template<bool BF>
__device__ __forceinline__ float nodeh(const void* x, const void* nw, int n,
                                       float v0, float v1, float v2) {
    return fmaf(ldf<BF>(x, n*3+2), v2,
           fmaf(ldf<BF>(x, n*3+1), v1,
                ldf<BF>(x, n*3+0) * v0)) * ldf<BF>(nw, n);
}

// K4: round-q ecc accumulation
template<bool BF, bool I64>
__device__ __forceinline__ void ecc_body(int q, const void* x, const void* nw,
                                         const void* v, const int* ei, const int* fc,
                                         const void* ew, const void* fw,
                                         const int* wsi, float* eccp,
                                         const unsigned short* pe, int cap_e,
                                         const unsigned short* pf, int cap_f) {
    int gq = blockIdx.x >> 5;
    int c  = blockIdx.x & (CHUNKS - 1);
    int g  = q * QG + gq;
    int t  = threadIdx.x;
    int d = t & 63, bg = t >> 6;

    float v0 = ldf<BF>(v, d);
    float v1 = ldf<BF>(v, ND + d);
    float v2 = ldf<BF>(v, 2 * ND + d);
    float linc0 = (-1.0f + (float)(bg * 16) / 31.0f) * KLOG;
    const float kdec = __builtin_amdgcn_exp2f(-DLT);

    float acc[8] = {0.f,0.f,0.f,0.f,0.f,0.f,0.f,0.f};

    int ns = wsi[NOFS_OFF + g], nend = wsi[NOFS_OFF + g + 1];
    for (int i = ns + c; i < nend; i += CHUNKS)
        accum8(nodeh<BF>(x, nw, i, v0, v1, v2), 1.0f, linc0, kdec, acc);

    int eb = wsi[O32_OFF + q*QG];
    int es = min(wsi[O32_OFF + g] - eb, cap_e);
    int ee = min(wsi[O32_OFF + g + 1] - eb, cap_e);
    for (int i = es + c; i < ee; i += CHUNKS) {
        int e = pe[i];
        int a = clamp_node(ldi<I64>(ei, e)), b = clamp_node(ldi<I64>(ei, NE + e));
        float h = fmaxf(nodeh<BF>(x, nw, a, v0, v1, v2), nodeh<BF>(x, nw, b, v0, v1, v2))
                  * ldf<BF>(ew, e);
        accum8(h, -1.0f, linc0, kdec, acc);
    }
    int fb = wsi[O32_OFF + 33 + q*QG];
    int fs0 = min(wsi[O32_OFF + 33 + g] - fb, cap_f);
    int fe = min(wsi[O32_OFF + 33 + g + 1] - fb, cap_f);
    for (int i = fs0 + c; i < fe; i += CHUNKS) {
        int f = pf[i];
        int a = clamp_node(ldi<I64>(fc, f)), b = clamp_node(ldi<I64>(fc, NF + f));
        int cc = clamp_node(ldi<I64>(fc, 2*NF + f));
        float h = fmaxf(fmaxf(nodeh<BF>(x, nw, a, v0, v1, v2),
                              nodeh<BF>(x, nw, b, v0, v1, v2)),
                        nodeh<BF>(x, nw, cc, v0, v1, v2)) * ldf<BF>(fw, f);
        accum8(h, 1.0f, linc0, kdec, acc);
    }
#pragma unroll
    for (int j = 0; j < 8; j++)
        atomicAdd(&eccp[gq * (NB * ND) + (bg * 8 + j) * ND + d], acc[j]);
}
__global__ __launch_bounds__(256) void k_ecc(int q, const void* __restrict__ x,
                                             const void* __restrict__ nw,
                                             const void* __restrict__ v,
                                             const int* __restrict__ ei,
                                             const int* __restrict__ fc,
                                             const void* __restrict__ ew,
                                             const void* __restrict__ fw,
                                             const int* __restrict__ wsi,
                                             float* __restrict__ eccp,
                                             const unsigned short* __restrict__ pe, int cap_e,
                                             const unsigned short* __restrict__ pf, int cap_f,
                                             const unsigned* __restrict__ flags) {
    unsigned bf = flags[0], i64 = flags[1];
    if (bf)  { if (i64) ecc_body<true,true >(q,x,nw,v,ei,fc,ew,fw,wsi,eccp,pe,cap_e,pf,cap_f);
               else     ecc_body<true,false>(q,x,nw,v,ei,fc,ew,fw,wsi,eccp,pe,cap_e,pf,cap_f); }
    else     { if (i64) ecc_body<false,true >(q,x,nw,v,ei,fc,ew,fw,wsi,eccp,pe,cap_e,pf,cap_f);
               else     ecc_body<false,false>(q,x,nw,v,ei,fc,ew,fw,wsi,eccp,pe,cap_e,pf,cap_f); }
}

// K5: flush round partials to flat region of d_out (dtype per flag); re-zero
__global__ __launch_bounds__(256) void k_flush(int q, float* __restrict__ eccp,
                                               unsigned* __restrict__ wsu,
                                               void* __restrict__ outv,
                                               const unsigned* __restrict__ flags) {
    int idx = blockIdx.x * 256 + threadIdx.x;
    if (idx < QG * NB * ND) {
        int gq = idx >> 11, rest = idx & 2047;
        int oi = NG * NCLS + (q * QG + gq) * (NB * ND) + rest;
        float val = eccp[idx];
        if (flags[0]) ((__hip_bfloat16*)outv)[oi] = __float2bfloat16(val);
        else          ((float*)outv)[oi] = val;
        eccp[idx] = 0.0f;
    }
    if (idx < 16) wsu[CUR_OFF + idx] = 0u;
}

// K6: MLP head; flat read back from d_out
template<bool BF>
__device__ __forceinline__ void mlp_body(const void* W1, const void* b1,
                                         const void* W2, const void* b2, void* outv) {
    __shared__ float fs[NB * ND];
    __shared__ float hs[HIDN];
    int g = blockIdx.x, t = threadIdx.x;

    for (int j = t; j < NB * ND; j += 256)
        fs[j] = ldf<BF>(outv, NG * NCLS + g * (NB * ND) + j);
    __syncthreads();

    float acc = ldf<BF>(b1, t);
    if (BF) {
        const uint4* wv = (const uint4*)((const __hip_bfloat16*)W1 + (size_t)t * (NB * ND));
#pragma unroll 4
        for (int qq = 0; qq < (NB * ND) / 8; qq++) {
            uint4 u = wv[qq];
            int j = qq * 8;
            acc = fmaf(__uint_as_float(u.x << 16),          fs[j + 0], acc);
            acc = fmaf(__uint_as_float(u.x & 0xffff0000u),  fs[j + 1], acc);
            acc = fmaf(__uint_as_float(u.y << 16),          fs[j + 2], acc);
            acc = fmaf(__uint_as_float(u.y & 0xffff0000u),  fs[j + 3], acc);
            acc = fmaf(__uint_as_float(u.z << 16),          fs[j + 4], acc);
            acc = fmaf(__uint_as_float(u.z & 0xffff0000u),  fs[j + 5], acc);
            acc = fmaf(__uint_as_float(u.w << 16),          fs[j + 6], acc);
            acc = fmaf(__uint_as_float(u.w & 0xffff0000u),  fs[j + 7], acc);
        }
    } else {
        const float4* wv = (const float4*)((const float*)W1 + (size_t)t * (NB * ND));
#pragma unroll 4
        for (int qq = 0; qq < (NB * ND) / 4; qq++) {
            float4 u = wv[qq];
            int j = qq * 4;
            acc = fmaf(u.x, fs[j + 0], acc);
            acc = fmaf(u.y, fs[j + 1], acc);
            acc = fmaf(u.z, fs[j + 2], acc);
            acc = fmaf(u.w, fs[j + 3], acc);
        }
    }
    hs[t] = fmaxf(acc, 0.0f);
    __syncthreads();

    if (t < NCLS) {
        float a2 = ldf<BF>(b2, t);
        for (int i = 0; i < HIDN; i++)
            a2 = fmaf(hs[i], ldf<BF>(W2, t * HIDN + i), a2);
        if (BF) ((__hip_bfloat16*)outv)[g * NCLS + t] = __float2bfloat16(a2);
        else    ((float*)outv)[g * NCLS + t] = a2;
    }
}
__global__ __launch_bounds__(256) void k_mlp(const void* __restrict__ W1,
                                             const void* __restrict__ b1,
                                             const void* __restrict__ W2,
                                             const void* __restrict__ b2,
                                             void* __restrict__ outv,
                                             const unsigned* __restrict__ flags) {
    if (flags[0]) mlp_body<true>(W1, b1, W2, b2, outv);
    else          mlp_body<false>(W1, b1, W2, b2, outv);
}

extern "C" void kernel_launch(void* const* d_in, const int* in_sizes, int n_in,
                              void* d_out, int out_size, void* d_ws, size_t ws_size,
                              hipStream_t stream) {
    const void* x  = d_in[0];
    const void* nw = d_in[1];
    const void* ew = d_in[2];
    const void* fw = d_in[3];
    const void* v  = d_in[4];
    const void* W1 = d_in[5];
    const void* b1 = d_in[6];
    const void* W2 = d_in[7];
    const void* b2 = d_in[8];
    const int* ei    = (const int*)d_in[9];
    const int* fc    = (const int*)d_in[10];
    const int* batch = (const int*)d_in[11];

    float*    wsf = (float*)d_ws;
    unsigned* wsu = (unsigned*)d_ws;
    int*      wsi = (int*)d_ws;
    float*    eccp  = wsf + ECCP_OFF;
    unsigned* flags = wsu + FLG_OFF;

    int total_words = (int)(ws_size / 4);
    int avail = total_words - PERM_OFF;
    if (avail < 0) avail = 0;
    int cap_e, cap_f;
    if (avail >= 40000) { cap_e = NE; cap_f = NF; }
    else {
        int we = avail * 3 / 5;
        cap_e = we * 2; if (cap_e > NE) cap_e = NE;
        cap_f = (avail - (cap_e + 1) / 2) * 2;
        if (cap_f > NF) cap_f = NF;
        if (cap_f < 0) cap_f = 0;
    }
    unsigned short* pe = (unsigned short*)(wsi + PERM_OFF);
    unsigned short* pf = pe + (((cap_e + 1) / 2) * 2);

    k_detect<<<1, 256, 0, stream>>>((const unsigned*)x, (const unsigned*)ei, flags);
    k_init<<<(ZERO_WORDS + 255) / 256, 256, 0, stream>>>(batch, wsf, wsi, flags);

    int efb = (NE + NF + 255) / 256;
    k_hist32<<<efb, 256, 0, stream>>>(ei, fc, batch, wsu, flags);
    k_prefix32<<<1, 64, 0, stream>>>(wsu, wsi);

    for (int q = 0; q < 4; q++) {
        k_scatter<<<efb, 256, 0, stream>>>(q, ei, fc, batch, wsi, wsu, pe, cap_e, pf, cap_f, flags);
        k_ecc<<<QG * CHUNKS, 256, 0, stream>>>(q, x, nw, v, ei, fc, ew, fw,
                                               wsi, eccp, pe, cap_e, pf, cap_f, flags);
        k_flush<<<(QG * NB * ND + 255) / 256, 256, 0, stream>>>(q, eccp, wsu, d_out, flags);
    }

    k_mlp<<<NG, 256, 0, stream>>>(W1, b1, W2, b2, d_out, flags);
}

// Round 6
// 272.316 us; speedup vs baseline: 1.5498x; 1.5498x over previous
//
#include <hip/hip_runtime.h>
#include <hip/hip_bf16.h>

// ---- problem constants ----
constexpr int NN = 16000, NE = 48000, NF = 32000;
constexpr int ND = 64, NB = 32, NG = 32;
constexpr int HIDN = 256, NCLS = 10;
constexpr int QG = 8;                         // graphs per round (4 rounds)
constexpr int CHB = 64;                       // chunk-blocks per graph in k_ecc
constexpr int EFB = (NE + NF + 255) / 256;    // 313 scatter blocks
constexpr int FLB = (QG * NB * ND) / 256;     // 64 flush blocks
constexpr float KLOG = 144.26950408889634f;   // 100 * log2(e)
constexpr float DLT  = 9.307710457348151f;    // (2/31) * KLOG

// ---- ws word layout ----
constexpr int ECCP_OFF = 0;                   // [16384] f32 round partials (64 KB)
constexpr int C32_OFF  = 16384;               // [64]  u32 hist (e:0..31, f:32..63)
constexpr int O32_OFF  = 16448;               // [66]  i32 offsets (e:0..32, f:33..65)
constexpr int CUR_OFF  = 16514;               // [64]  u32 cursors, 16 per round
constexpr int ZERO_WORDS = 16578;             // zero ECCP+C32+O32+CUR
constexpr int NOFS_OFF = 16578;               // [33]  i32 node boundaries
constexpr int PERM_OFF = 16612;               // u16 perm_e/perm_f tail (host-sized)

__device__ __forceinline__ int clamp_node(int n) {
    return ((unsigned)n < (unsigned)NN) ? n : 0;
}
template<bool BF> __device__ __forceinline__ float ldf(const void* p, int i) {
    return BF ? __bfloat162float(((const __hip_bfloat16*)p)[i]) : ((const float*)p)[i];
}
template<bool I64> __device__ __forceinline__ int ldi(const int* p, int i) {
    return I64 ? p[2 * i] : p[i];
}

// per-block dtype self-detection (wave-uniform result via ballot)
__device__ __forceinline__ bool detect_bf(const void* xp) {
    const unsigned* xw = (const unsigned*)xp;
    unsigned w = xw[threadIdx.x & 63];
    return __ballot(((w >> 23) & 0xFFu) >= 200u) != 0ull;   // bf16-pair exponent signature
}
__device__ __forceinline__ bool detect_i64(const int* eip) {
    const unsigned* eiw = (const unsigned*)eip;
    unsigned o = eiw[2 * (threadIdx.x & 63) + 1];
    return __ballot(o != 0u) == 0ull;                        // zero odd words => int64
}

template<bool BF>
__device__ __forceinline__ float nodeh(const void* x, const void* nw, int n,
                                       float v0, float v1, float v2) {
    return fmaf(ldf<BF>(x, n*3+2), v2,
           fmaf(ldf<BF>(x, n*3+1), v1,
                ldf<BF>(x, n*3+0) * v0)) * ldf<BF>(nw, n);
}
template<bool BF, bool I64>
__device__ __forceinline__ float edgeh(const void* x, const void* nw, const int* ei,
                                       const void* ew, int e,
                                       float v0, float v1, float v2) {
    int a = clamp_node(ldi<I64>(ei, e)), b = clamp_node(ldi<I64>(ei, NE + e));
    return fmaxf(nodeh<BF>(x, nw, a, v0, v1, v2), nodeh<BF>(x, nw, b, v0, v1, v2))
           * ldf<BF>(ew, e);
}
template<bool BF, bool I64>
__device__ __forceinline__ float faceh(const void* x, const void* nw, const int* fc,
                                       const void* fw, int f,
                                       float v0, float v1, float v2) {
    int a = clamp_node(ldi<I64>(fc, f)), b = clamp_node(ldi<I64>(fc, NF + f));
    int c = clamp_node(ldi<I64>(fc, 2*NF + f));
    return fmaxf(fmaxf(nodeh<BF>(x, nw, a, v0, v1, v2), nodeh<BF>(x, nw, b, v0, v1, v2)),
                 nodeh<BF>(x, nw, c, v0, v1, v2)) * ldf<BF>(fw, f);
}

// 32 bumps per thread: 4 ladder groups of 8, one exp2 each; clamp [-60,126] is
// exact in the non-saturated window (max needed t0 = 9.31*7+15 = 80 < 126).
__device__ __forceinline__ void accum32(float h, float s, float* acc) {
    float hk = h * KLOG;
    const float kdec = __builtin_amdgcn_exp2f(-DLT);
#pragma unroll
    for (int k = 0; k < 4; k++) {
        float linc0 = (-1.0f + (float)(16 * k) / 31.0f) * KLOG;
        float t0 = fminf(fmaxf(hk - linc0, -60.0f), 126.0f);
        float e2 = __builtin_amdgcn_exp2f(t0);
#pragma unroll
        for (int j = 0; j < 8; j++) {
            acc[k*8+j] = fmaf(s, __builtin_amdgcn_rcpf(1.0f + e2), acc[k*8+j]);
            e2 *= kdec;
        }
    }
}

// K0: zero head + node range boundaries (self-detect int width)
template<bool I64>
__device__ __forceinline__ void init_body(const int* batch, float* wsf, int* wsi) {
    int gid = blockIdx.x * 256 + threadIdx.x;
    if (gid < ZERO_WORDS) wsf[gid] = 0.0f;
    if (gid < NN) {
        int gn = ldi<I64>(batch, gid) & (NG - 1);
        int gp = (gid > 0) ? (ldi<I64>(batch, gid - 1) & (NG - 1)) : -1;
        for (int gg = gp + 1; gg <= gn; gg++) wsi[NOFS_OFF + gg] = gid;
        if (gid == NN - 1)
            for (int gg = gn + 1; gg <= NG; gg++) wsi[NOFS_OFF + gg] = NN;
    }
}
__global__ __launch_bounds__(256) void k_init(const int* __restrict__ batch,
                                              float* __restrict__ wsf,
                                              int* __restrict__ wsi,
                                              const int* __restrict__ ei) {
    if (detect_i64(ei)) init_body<true>(batch, wsf, wsi);
    else                init_body<false>(batch, wsf, wsi);
}

// K1: 32-bin histograms for edges and faces
template<bool I64>
__device__ __forceinline__ void hist_body(const int* ei, const int* fc, const int* batch,
                                          unsigned* wsu) {
    __shared__ unsigned hb[64];
    int t = threadIdx.x;
    if (t < 64) hb[t] = 0;
    __syncthreads();
    int id = blockIdx.x * 256 + t;
    if (id < NE + NF) {
        if (id < NE) atomicAdd(&hb[ldi<I64>(batch, clamp_node(ldi<I64>(ei, id))) & 31], 1u);
        else         atomicAdd(&hb[32 + (ldi<I64>(batch, clamp_node(ldi<I64>(fc, id - NE))) & 31)], 1u);
    }
    __syncthreads();
    if (t < 64 && hb[t]) atomicAdd(&wsu[C32_OFF + t], hb[t]);
}
__global__ __launch_bounds__(256) void k_hist32(const int* __restrict__ ei,
                                                const int* __restrict__ fc,
                                                const int* __restrict__ batch,
                                                unsigned* __restrict__ wsu) {
    if (detect_i64(ei)) hist_body<true>(ei, fc, batch, wsu);
    else                hist_body<false>(ei, fc, batch, wsu);
}

// K2: exclusive prefix for both histograms
__global__ void k_prefix32(const unsigned* __restrict__ wsu, int* __restrict__ wsi) {
    if (threadIdx.x == 0) {
        int acc = 0;
        for (int i = 0; i < NG; i++) { wsi[O32_OFF + i] = acc; acc += (int)wsu[C32_OFF + i]; }
        wsi[O32_OFF + NG] = acc;
        acc = 0;
        for (int i = 0; i < NG; i++) { wsi[O32_OFF + 33 + i] = acc; acc += (int)wsu[C32_OFF + 32 + i]; }
        wsi[O32_OFF + 33 + NG] = acc;
    }
}

// scatter body (round qs; per-round cursor bank)
template<bool I64>
__device__ __forceinline__ void scatter_body(int qs, const int* ei, const int* fc,
                                             const int* batch, const int* wsi,
                                             unsigned* wsu,
                                             unsigned short* pe, int cap_e,
                                             unsigned short* pf, int cap_f) {
    __shared__ unsigned cnt[16];
    __shared__ unsigned base[16];
    int t = threadIdx.x;
    if (t < 16) cnt[t] = 0;
    __syncthreads();
    int id = blockIdx.x * 256 + t;
    int bin = 0; unsigned rank = 0; bool active = false; bool isf = false;
    if (id < NE + NF) {
        int g;
        if (id < NE) g = ldi<I64>(batch, clamp_node(ldi<I64>(ei, id))) & 31;
        else       { g = ldi<I64>(batch, clamp_node(ldi<I64>(fc, id - NE))) & 31; isf = true; }
        if ((g >> 3) == qs) {
            active = true;
            bin = (g & 7) + (isf ? 8 : 0);
            rank = atomicAdd(&cnt[bin], 1u);
        }
    }
    __syncthreads();
    if (t < 16) base[t] = cnt[t] ? atomicAdd(&wsu[CUR_OFF + qs*16 + t], cnt[t]) : 0u;
    __syncthreads();
    if (active) {
        int gq = bin & 7;
        if (!isf) {
            int pos = (wsi[O32_OFF + qs*QG + gq] - wsi[O32_OFF + qs*QG]) + (int)(base[bin] + rank);
            if (pos >= 0 && pos < cap_e) pe[pos] = (unsigned short)id;
        } else {
            int pos = (wsi[O32_OFF + 33 + qs*QG + gq] - wsi[O32_OFF + 33 + qs*QG]) + (int)(base[bin] + rank);
            if (pos >= 0 && pos < cap_f) pf[pos] = (unsigned short)(id - NE);
        }
    }
}

// flush body (round qf): eccp -> out flat region; re-zero eccp
template<bool BF>
__device__ __forceinline__ void flush_body(int qf, int fb, float* eccp, void* outv) {
    int idx = fb * 256 + threadIdx.x;
    int gq = idx >> 11, rest = idx & 2047;
    int oi = NG * NCLS + (qf * QG + gq) * (NB * ND) + rest;
    float val = eccp[idx];
    if (BF) ((__hip_bfloat16*)outv)[oi] = __float2bfloat16(val);
    else    ((float*)outv)[oi] = val;
    eccp[idx] = 0.0f;
}

// K3: merged scatter(qs) + flush(qf) — independent work, one launch
__global__ __launch_bounds__(256) void k_sf(int qs, int qf,
                                            const int* __restrict__ ei,
                                            const int* __restrict__ fc,
                                            const int* __restrict__ batch,
                                            const int* __restrict__ wsi,
                                            unsigned* __restrict__ wsu,
                                            unsigned short* __restrict__ pe, int cap_e,
                                            unsigned short* __restrict__ pf, int cap_f,
                                            float* __restrict__ eccp,
                                            void* __restrict__ outv,
                                            const void* __restrict__ x) {
    if (blockIdx.x < EFB) {
        if (qs >= 0) {
            if (detect_i64(ei)) scatter_body<true>(qs, ei, fc, batch, wsi, wsu, pe, cap_e, pf, cap_f);
            else                scatter_body<false>(qs, ei, fc, batch, wsi, wsu, pe, cap_e, pf, cap_f);
        }
    } else {
        if (qf >= 0) {
            if (detect_bf(x)) flush_body<true>(qf, blockIdx.x - EFB, eccp, outv);
            else              flush_body<false>(qf, blockIdx.x - EFB, eccp, outv);
        }
    }
}

// K4: ecc accumulation, wave-per-element-stream. block = 4 waves, lane = dir,
// each thread holds all 32 bump accumulators. grid = QG*CHB per round.
template<bool BF, bool I64>
__device__ __forceinline__ void ecc_body(int q, const void* x, const void* nw,
                                         const void* v, const int* ei, const int* fc,
                                         const void* ew, const void* fw,
                                         const int* wsi, float* eccp,
                                         const unsigned short* pe, int cap_e,
                                         const unsigned short* pf, int cap_f) {
    int t = threadIdx.x;
    int d = t & 63;
    int w = __builtin_amdgcn_readfirstlane(t) >> 6;   // wave id, provably scalar
    int gq = blockIdx.x >> 6;                         // / CHB
    int cb = blockIdx.x & (CHB - 1);
    int g  = q * QG + gq;
    int sid = cb * 4 + w;                             // wave-stream id 0..255
    const int S = CHB * 4;                            // 256 streams per graph

    float v0 = ldf<BF>(v, d);
    float v1 = ldf<BF>(v, ND + d);
    float v2 = ldf<BF>(v, 2 * ND + d);

    float acc[32];
#pragma unroll
    for (int j = 0; j < 32; j++) acc[j] = 0.0f;

    // nodes (+1): contiguous range, no perm
    int ns = wsi[NOFS_OFF + g], nend = wsi[NOFS_OFF + g + 1];
    int i = ns + sid;
    for (; i + S < nend; i += 2 * S) {
        float h1 = nodeh<BF>(x, nw, i,     v0, v1, v2);
        float h2 = nodeh<BF>(x, nw, i + S, v0, v1, v2);
        accum32(h1, 1.0f, acc);
        accum32(h2, 1.0f, acc);
    }
    if (i < nend) accum32(nodeh<BF>(x, nw, i, v0, v1, v2), 1.0f, acc);

    // edges (-1)
    int eb = wsi[O32_OFF + q*QG];
    int es = min(wsi[O32_OFF + g] - eb, cap_e);
    int ee = min(wsi[O32_OFF + g + 1] - eb, cap_e);
    i = es + sid;
    for (; i + S < ee; i += 2 * S) {
        int e1 = pe[i], e2 = pe[i + S];
        float h1 = edgeh<BF,I64>(x, nw, ei, ew, e1, v0, v1, v2);
        float h2 = edgeh<BF,I64>(x, nw, ei, ew, e2, v0, v1, v2);
        accum32(h1, -1.0f, acc);
        accum32(h2, -1.0f, acc);
    }
    if (i < ee) accum32(edgeh<BF,I64>(x, nw, ei, ew, pe[i], v0, v1, v2), -1.0f, acc);

    // faces (+1)
    int fb = wsi[O32_OFF + 33 + q*QG];
    int fs0 = min(wsi[O32_OFF + 33 + g] - fb, cap_f);
    int fe = min(wsi[O32_OFF + 33 + g + 1] - fb, cap_f);
    i = fs0 + sid;
    for (; i + S < fe; i += 2 * S) {
        int f1 = pf[i], f2 = pf[i + S];
        float h1 = faceh<BF,I64>(x, nw, fc, fw, f1, v0, v1, v2);
        float h2 = faceh<BF,I64>(x, nw, fc, fw, f2, v0, v1, v2);
        accum32(h1, 1.0f, acc);
        accum32(h2, 1.0f, acc);
    }
    if (i < fe) accum32(faceh<BF,I64>(x, nw, fc, fw, pf[i], v0, v1, v2), 1.0f, acc);

    // block reduction: 4 waves -> 1, then 2048 global atomics per block
    __shared__ float red[4][NB * ND];
#pragma unroll
    for (int j = 0; j < 32; j++) red[w][j * 64 + d] = acc[j];
    __syncthreads();
    for (int jj = t; jj < NB * ND; jj += 256) {
        float sum = red[0][jj] + red[1][jj] + red[2][jj] + red[3][jj];
        atomicAdd(&eccp[gq * (NB * ND) + jj], sum);
    }
}
__global__ __launch_bounds__(256) void k_ecc(int q, const void* __restrict__ x,
                                             const void* __restrict__ nw,
                                             const void* __restrict__ v,
                                             const int* __restrict__ ei,
                                             const int* __restrict__ fc,
                                             const void* __restrict__ ew,
                                             const void* __restrict__ fw,
                                             const int* __restrict__ wsi,
                                             float* __restrict__ eccp,
                                             const unsigned short* __restrict__ pe, int cap_e,
                                             const unsigned short* __restrict__ pf, int cap_f) {
    bool bf = detect_bf(x), i64 = detect_i64(ei);
    if (bf)  { if (i64) ecc_body<true,true >(q,x,nw,v,ei,fc,ew,fw,wsi,eccp,pe,cap_e,pf,cap_f);
               else     ecc_body<true,false>(q,x,nw,v,ei,fc,ew,fw,wsi,eccp,pe,cap_e,pf,cap_f); }
    else     { if (i64) ecc_body<false,true >(q,x,nw,v,ei,fc,ew,fw,wsi,eccp,pe,cap_e,pf,cap_f);
               else     ecc_body<false,false>(q,x,nw,v,ei,fc,ew,fw,wsi,eccp,pe,cap_e,pf,cap_f); }
}

// K5: MLP head; flat read back from d_out
template<bool BF>
__device__ __forceinline__ void mlp_body(const void* W1, const void* b1,
                                         const void* W2, const void* b2, void* outv) {
    __shared__ float fs[NB * ND];
    __shared__ float hs[HIDN];
    int g = blockIdx.x, t = threadIdx.x;

    for (int j = t; j < NB * ND; j += 256)
        fs[j] = ldf<BF>(outv, NG * NCLS + g * (NB * ND) + j);
    __syncthreads();

    float acc = ldf<BF>(b1, t);
    if (BF) {
        const uint4* wv = (const uint4*)((const __hip_bfloat16*)W1 + (size_t)t * (NB * ND));
#pragma unroll 4
        for (int qq = 0; qq < (NB * ND) / 8; qq++) {
            uint4 u = wv[qq];
            int j = qq * 8;
            acc = fmaf(__uint_as_float(u.x << 16),          fs[j + 0], acc);
            acc = fmaf(__uint_as_float(u.x & 0xffff0000u),  fs[j + 1], acc);
            acc = fmaf(__uint_as_float(u.y << 16),          fs[j + 2], acc);
            acc = fmaf(__uint_as_float(u.y & 0xffff0000u),  fs[j + 3], acc);
            acc = fmaf(__uint_as_float(u.z << 16),          fs[j + 4], acc);
            acc = fmaf(__uint_as_float(u.z & 0xffff0000u),  fs[j + 5], acc);
            acc = fmaf(__uint_as_float(u.w << 16),          fs[j + 6], acc);
            acc = fmaf(__uint_as_float(u.w & 0xffff0000u),  fs[j + 7], acc);
        }
    } else {
        const float4* wv = (const float4*)((const float*)W1 + (size_t)t * (NB * ND));
#pragma unroll 4
        for (int qq = 0; qq < (NB * ND) / 4; qq++) {
            float4 u = wv[qq];
            int j = qq * 4;
            acc = fmaf(u.x, fs[j + 0], acc);
            acc = fmaf(u.y, fs[j + 1], acc);
            acc = fmaf(u.z, fs[j + 2], acc);
            acc = fmaf(u.w, fs[j + 3], acc);
        }
    }
    hs[t] = fmaxf(acc, 0.0f);
    __syncthreads();

    if (t < NCLS) {
        float a2 = ldf<BF>(b2, t);
        for (int i = 0; i < HIDN; i++)
            a2 = fmaf(hs[i], ldf<BF>(W2, t * HIDN + i), a2);
        if (BF) ((__hip_bfloat16*)outv)[g * NCLS + t] = __float2bfloat16(a2);
        else    ((float*)outv)[g * NCLS + t] = a2;
    }
}
__global__ __launch_bounds__(256) void k_mlp(const void* __restrict__ W1,
                                             const void* __restrict__ b1,
                                             const void* __restrict__ W2,
                                             const void* __restrict__ b2,
                                             void* __restrict__ outv,
                                             const void* __restrict__ x) {
    if (detect_bf(x)) mlp_body<true>(W1, b1, W2, b2, outv);
    else              mlp_body<false>(W1, b1, W2, b2, outv);
}

extern "C" void kernel_launch(void* const* d_in, const int* in_sizes, int n_in,
                              void* d_out, int out_size, void* d_ws, size_t ws_size,
                              hipStream_t stream) {
    const void* x  = d_in[0];
    const void* nw = d_in[1];
    const void* ew = d_in[2];
    const void* fw = d_in[3];
    const void* v  = d_in[4];
    const void* W1 = d_in[5];
    const void* b1 = d_in[6];
    const void* W2 = d_in[7];
    const void* b2 = d_in[8];
    const int* ei    = (const int*)d_in[9];
    const int* fc    = (const int*)d_in[10];
    const int* batch = (const int*)d_in[11];

    float*    wsf = (float*)d_ws;
    unsigned* wsu = (unsigned*)d_ws;
    int*      wsi = (int*)d_ws;
    float*    eccp = wsf + ECCP_OFF;

    int total_words = (int)(ws_size / 4);
    int avail = total_words - PERM_OFF;
    if (avail < 0) avail = 0;
    int cap_e, cap_f;
    if (avail >= 40000) { cap_e = NE; cap_f = NF; }
    else {
        int we = avail * 3 / 5;
        cap_e = we * 2; if (cap_e > NE) cap_e = NE;
        cap_f = (avail - (cap_e + 1) / 2) * 2;
        if (cap_f > NF) cap_f = NF;
        if (cap_f < 0) cap_f = 0;
    }
    unsigned short* pe = (unsigned short*)(wsi + PERM_OFF);
    unsigned short* pf = pe + (((cap_e + 1) / 2) * 2);

    k_init<<<(ZERO_WORDS + 255) / 256, 256, 0, stream>>>(batch, wsf, wsi, ei);
    k_hist32<<<EFB, 256, 0, stream>>>(ei, fc, batch, wsu);
    k_prefix32<<<1, 64, 0, stream>>>(wsu, wsi);

    for (int q = 0; q < 4; q++) {
        // scatter round q; flush round q-1 (independent work, one launch)
        k_sf<<<EFB + FLB, 256, 0, stream>>>(q, q - 1, ei, fc, batch, wsi, wsu,
                                            pe, cap_e, pf, cap_f, eccp, d_out, x);
        k_ecc<<<QG * CHB, 256, 0, stream>>>(q, x, nw, v, ei, fc, ew, fw,
                                            wsi, eccp, pe, cap_e, pf, cap_f);
    }
    // final flush (no scatter)
    k_sf<<<EFB + FLB, 256, 0, stream>>>(-1, 3, ei, fc, batch, wsi, wsu,
                                        pe, cap_e, pf, cap_f, eccp, d_out, x);

    k_mlp<<<NG, 256, 0, stream>>>(W1, b1, W2, b2, d_out, x);
}

// Round 7
// 221.681 us; speedup vs baseline: 1.9037x; 1.2284x over previous
//
#include <hip/hip_runtime.h>
#include <hip/hip_bf16.h>

// ---- problem constants ----
constexpr int NN = 16000, NE = 48000, NF = 32000;
constexpr int ND = 64, NB = 32, NG = 32;
constexpr int HIDN = 256, NCLS = 10;
constexpr int QG = 8;                         // graphs per round (4 rounds)
constexpr int CHB = 64;                       // chunk-blocks per graph in k_ecc
constexpr int EFB = (NE + NF + 255) / 256;    // 313 scatter blocks
constexpr int FLB = (QG * NB * ND) / 256;     // 64 flush blocks
constexpr float KLOG = 144.26950408889634f;   // 100 * log2(e)
constexpr float DLT  = 9.307710457348151f;    // (2/31) * KLOG

// ---- ws word layout ----
constexpr int ECCP_OFF = 0;                   // [16384] f32 round partials (64 KB)
constexpr int HBUF_OFF = 0;                   // h[32][256] f32 — reuses ECCP after final flush
constexpr int C32_OFF  = 16384;               // [64]  u32 hist (e:0..31, f:32..63)
constexpr int O32_OFF  = 16448;               // [66]  i32 offsets (e:0..32, f:33..65)
constexpr int CUR_OFF  = 16514;               // [64]  u32 cursors, 16 per round
constexpr int ZERO_WORDS = 16578;             // zero ECCP+C32+O32+CUR
constexpr int NOFS_OFF = 16578;               // [33]  i32 node boundaries
constexpr int PERM_OFF = 16612;               // u16 perm_e/perm_f tail (host-sized)

__device__ __forceinline__ int clamp_node(int n) {
    return ((unsigned)n < (unsigned)NN) ? n : 0;
}
template<bool BF> __device__ __forceinline__ float ldf(const void* p, int i) {
    return BF ? __bfloat162float(((const __hip_bfloat16*)p)[i]) : ((const float*)p)[i];
}
template<bool I64> __device__ __forceinline__ int ldi(const int* p, int i) {
    return I64 ? p[2 * i] : p[i];
}

// per-block dtype self-detection (wave-uniform result via ballot)
__device__ __forceinline__ bool detect_bf(const void* xp) {
    const unsigned* xw = (const unsigned*)xp;
    unsigned w = xw[threadIdx.x & 63];
    return __ballot(((w >> 23) & 0xFFu) >= 200u) != 0ull;   // bf16-pair exponent signature
}
__device__ __forceinline__ bool detect_i64(const int* eip) {
    const unsigned* eiw = (const unsigned*)eip;
    unsigned o = eiw[2 * (threadIdx.x & 63) + 1];
    return __ballot(o != 0u) == 0ull;                        // zero odd words => int64
}

template<bool BF>
__device__ __forceinline__ float nodeh(const void* x, const void* nw, int n,
                                       float v0, float v1, float v2) {
    return fmaf(ldf<BF>(x, n*3+2), v2,
           fmaf(ldf<BF>(x, n*3+1), v1,
                ldf<BF>(x, n*3+0) * v0)) * ldf<BF>(nw, n);
}
template<bool BF, bool I64>
__device__ __forceinline__ float edgeh(const void* x, const void* nw, const int* ei,
                                       const void* ew, int e,
                                       float v0, float v1, float v2) {
    int a = clamp_node(ldi<I64>(ei, e)), b = clamp_node(ldi<I64>(ei, NE + e));
    return fmaxf(nodeh<BF>(x, nw, a, v0, v1, v2), nodeh<BF>(x, nw, b, v0, v1, v2))
           * ldf<BF>(ew, e);
}
template<bool BF, bool I64>
__device__ __forceinline__ float faceh(const void* x, const void* nw, const int* fc,
                                       const void* fw, int f,
                                       float v0, float v1, float v2) {
    int a = clamp_node(ldi<I64>(fc, f)), b = clamp_node(ldi<I64>(fc, NF + f));
    int c = clamp_node(ldi<I64>(fc, 2*NF + f));
    return fmaxf(fmaxf(nodeh<BF>(x, nw, a, v0, v1, v2), nodeh<BF>(x, nw, b, v0, v1, v2)),
                 nodeh<BF>(x, nw, c, v0, v1, v2)) * ldf<BF>(fw, f);
}

// 32 bumps per thread: 4 ladder groups of 8, one exp2 each
__device__ __forceinline__ void accum32(float h, float s, float* acc) {
    float hk = h * KLOG;
    const float kdec = __builtin_amdgcn_exp2f(-DLT);
#pragma unroll
    for (int k = 0; k < 4; k++) {
        float linc0 = (-1.0f + (float)(16 * k) / 31.0f) * KLOG;
        float t0 = fminf(fmaxf(hk - linc0, -60.0f), 126.0f);
        float e2 = __builtin_amdgcn_exp2f(t0);
#pragma unroll
        for (int j = 0; j < 8; j++) {
            acc[k*8+j] = fmaf(s, __builtin_amdgcn_rcpf(1.0f + e2), acc[k*8+j]);
            e2 *= kdec;
        }
    }
}

// K0: zero head + node range boundaries
template<bool I64>
__device__ __forceinline__ void init_body(const int* batch, float* wsf, int* wsi) {
    int gid = blockIdx.x * 256 + threadIdx.x;
    if (gid < ZERO_WORDS) wsf[gid] = 0.0f;
    if (gid < NN) {
        int gn = ldi<I64>(batch, gid) & (NG - 1);
        int gp = (gid > 0) ? (ldi<I64>(batch, gid - 1) & (NG - 1)) : -1;
        for (int gg = gp + 1; gg <= gn; gg++) wsi[NOFS_OFF + gg] = gid;
        if (gid == NN - 1)
            for (int gg = gn + 1; gg <= NG; gg++) wsi[NOFS_OFF + gg] = NN;
    }
}
__global__ __launch_bounds__(256) void k_init(const int* __restrict__ batch,
                                              float* __restrict__ wsf,
                                              int* __restrict__ wsi,
                                              const int* __restrict__ ei) {
    if (detect_i64(ei)) init_body<true>(batch, wsf, wsi);
    else                init_body<false>(batch, wsf, wsi);
}

// K1: 32-bin histograms for edges and faces
template<bool I64>
__device__ __forceinline__ void hist_body(const int* ei, const int* fc, const int* batch,
                                          unsigned* wsu) {
    __shared__ unsigned hb[64];
    int t = threadIdx.x;
    if (t < 64) hb[t] = 0;
    __syncthreads();
    int id = blockIdx.x * 256 + t;
    if (id < NE + NF) {
        if (id < NE) atomicAdd(&hb[ldi<I64>(batch, clamp_node(ldi<I64>(ei, id))) & 31], 1u);
        else         atomicAdd(&hb[32 + (ldi<I64>(batch, clamp_node(ldi<I64>(fc, id - NE))) & 31)], 1u);
    }
    __syncthreads();
    if (t < 64 && hb[t]) atomicAdd(&wsu[C32_OFF + t], hb[t]);
}
__global__ __launch_bounds__(256) void k_hist32(const int* __restrict__ ei,
                                                const int* __restrict__ fc,
                                                const int* __restrict__ batch,
                                                unsigned* __restrict__ wsu) {
    if (detect_i64(ei)) hist_body<true>(ei, fc, batch, wsu);
    else                hist_body<false>(ei, fc, batch, wsu);
}

// K2: exclusive prefix
__global__ void k_prefix32(const unsigned* __restrict__ wsu, int* __restrict__ wsi) {
    if (threadIdx.x == 0) {
        int acc = 0;
        for (int i = 0; i < NG; i++) { wsi[O32_OFF + i] = acc; acc += (int)wsu[C32_OFF + i]; }
        wsi[O32_OFF + NG] = acc;
        acc = 0;
        for (int i = 0; i < NG; i++) { wsi[O32_OFF + 33 + i] = acc; acc += (int)wsu[C32_OFF + 32 + i]; }
        wsi[O32_OFF + 33 + NG] = acc;
    }
}

// scatter body (round qs)
template<bool I64>
__device__ __forceinline__ void scatter_body(int qs, const int* ei, const int* fc,
                                             const int* batch, const int* wsi,
                                             unsigned* wsu,
                                             unsigned short* pe, int cap_e,
                                             unsigned short* pf, int cap_f) {
    __shared__ unsigned cnt[16];
    __shared__ unsigned base[16];
    int t = threadIdx.x;
    if (t < 16) cnt[t] = 0;
    __syncthreads();
    int id = blockIdx.x * 256 + t;
    int bin = 0; unsigned rank = 0; bool active = false; bool isf = false;
    if (id < NE + NF) {
        int g;
        if (id < NE) g = ldi<I64>(batch, clamp_node(ldi<I64>(ei, id))) & 31;
        else       { g = ldi<I64>(batch, clamp_node(ldi<I64>(fc, id - NE))) & 31; isf = true; }
        if ((g >> 3) == qs) {
            active = true;
            bin = (g & 7) + (isf ? 8 : 0);
            rank = atomicAdd(&cnt[bin], 1u);
        }
    }
    __syncthreads();
    if (t < 16) base[t] = cnt[t] ? atomicAdd(&wsu[CUR_OFF + qs*16 + t], cnt[t]) : 0u;
    __syncthreads();
    if (active) {
        int gq = bin & 7;
        if (!isf) {
            int pos = (wsi[O32_OFF + qs*QG + gq] - wsi[O32_OFF + qs*QG]) + (int)(base[bin] + rank);
            if (pos >= 0 && pos < cap_e) pe[pos] = (unsigned short)id;
        } else {
            int pos = (wsi[O32_OFF + 33 + qs*QG + gq] - wsi[O32_OFF + 33 + qs*QG]) + (int)(base[bin] + rank);
            if (pos >= 0 && pos < cap_f) pf[pos] = (unsigned short)(id - NE);
        }
    }
}

// flush body (round qf)
template<bool BF>
__device__ __forceinline__ void flush_body(int qf, int fb, float* eccp, void* outv) {
    int idx = fb * 256 + threadIdx.x;
    int gq = idx >> 11, rest = idx & 2047;
    int oi = NG * NCLS + (qf * QG + gq) * (NB * ND) + rest;
    float val = eccp[idx];
    if (BF) ((__hip_bfloat16*)outv)[oi] = __float2bfloat16(val);
    else    ((float*)outv)[oi] = val;
    eccp[idx] = 0.0f;
}

// K3: merged scatter(qs) + flush(qf)
__global__ __launch_bounds__(256) void k_sf(int qs, int qf,
                                            const int* __restrict__ ei,
                                            const int* __restrict__ fc,
                                            const int* __restrict__ batch,
                                            const int* __restrict__ wsi,
                                            unsigned* __restrict__ wsu,
                                            unsigned short* __restrict__ pe, int cap_e,
                                            unsigned short* __restrict__ pf, int cap_f,
                                            float* __restrict__ eccp,
                                            void* __restrict__ outv,
                                            const void* __restrict__ x) {
    if (blockIdx.x < EFB) {
        if (qs >= 0) {
            if (detect_i64(ei)) scatter_body<true>(qs, ei, fc, batch, wsi, wsu, pe, cap_e, pf, cap_f);
            else                scatter_body<false>(qs, ei, fc, batch, wsi, wsu, pe, cap_e, pf, cap_f);
        }
    } else {
        if (qf >= 0) {
            if (detect_bf(x)) flush_body<true>(qf, blockIdx.x - EFB, eccp, outv);
            else              flush_body<false>(qf, blockIdx.x - EFB, eccp, outv);
        }
    }
}

// K4: ecc accumulation, wave-per-element-stream
template<bool BF, bool I64>
__device__ __forceinline__ void ecc_body(int q, const void* x, const void* nw,
                                         const void* v, const int* ei, const int* fc,
                                         const void* ew, const void* fw,
                                         const int* wsi, float* eccp,
                                         const unsigned short* pe, int cap_e,
                                         const unsigned short* pf, int cap_f) {
    int t = threadIdx.x;
    int d = t & 63;
    int w = __builtin_amdgcn_readfirstlane(t) >> 6;
    int gq = blockIdx.x >> 6;
    int cb = blockIdx.x & (CHB - 1);
    int g  = q * QG + gq;
    int sid = cb * 4 + w;
    const int S = CHB * 4;

    float v0 = ldf<BF>(v, d);
    float v1 = ldf<BF>(v, ND + d);
    float v2 = ldf<BF>(v, 2 * ND + d);

    float acc[32];
#pragma unroll
    for (int j = 0; j < 32; j++) acc[j] = 0.0f;

    int ns = wsi[NOFS_OFF + g], nend = wsi[NOFS_OFF + g + 1];
    int i = ns + sid;
    for (; i + S < nend; i += 2 * S) {
        float h1 = nodeh<BF>(x, nw, i,     v0, v1, v2);
        float h2 = nodeh<BF>(x, nw, i + S, v0, v1, v2);
        accum32(h1, 1.0f, acc);
        accum32(h2, 1.0f, acc);
    }
    if (i < nend) accum32(nodeh<BF>(x, nw, i, v0, v1, v2), 1.0f, acc);

    int eb = wsi[O32_OFF + q*QG];
    int es = min(wsi[O32_OFF + g] - eb, cap_e);
    int ee = min(wsi[O32_OFF + g + 1] - eb, cap_e);
    i = es + sid;
    for (; i + S < ee; i += 2 * S) {
        int e1 = pe[i], e2 = pe[i + S];
        float h1 = edgeh<BF,I64>(x, nw, ei, ew, e1, v0, v1, v2);
        float h2 = edgeh<BF,I64>(x, nw, ei, ew, e2, v0, v1, v2);
        accum32(h1, -1.0f, acc);
        accum32(h2, -1.0f, acc);
    }
    if (i < ee) accum32(edgeh<BF,I64>(x, nw, ei, ew, pe[i], v0, v1, v2), -1.0f, acc);

    int fb = wsi[O32_OFF + 33 + q*QG];
    int fs0 = min(wsi[O32_OFF + 33 + g] - fb, cap_f);
    int fe = min(wsi[O32_OFF + 33 + g + 1] - fb, cap_f);
    i = fs0 + sid;
    for (; i + S < fe; i += 2 * S) {
        int f1 = pf[i], f2 = pf[i + S];
        float h1 = faceh<BF,I64>(x, nw, fc, fw, f1, v0, v1, v2);
        float h2 = faceh<BF,I64>(x, nw, fc, fw, f2, v0, v1, v2);
        accum32(h1, 1.0f, acc);
        accum32(h2, 1.0f, acc);
    }
    if (i < fe) accum32(faceh<BF,I64>(x, nw, fc, fw, pf[i], v0, v1, v2), 1.0f, acc);

    __shared__ float red[4][NB * ND];
#pragma unroll
    for (int j = 0; j < 32; j++) red[w][j * 64 + d] = acc[j];
    __syncthreads();
    for (int jj = t; jj < NB * ND; jj += 256) {
        float sum = red[0][jj] + red[1][jj] + red[2][jj] + red[3][jj];
        atomicAdd(&eccp[gq * (NB * ND) + jj], sum);
    }
}
__global__ __launch_bounds__(256) void k_ecc(int q, const void* __restrict__ x,
                                             const void* __restrict__ nw,
                                             const void* __restrict__ v,
                                             const int* __restrict__ ei,
                                             const int* __restrict__ fc,
                                             const void* __restrict__ ew,
                                             const void* __restrict__ fw,
                                             const int* __restrict__ wsi,
                                             float* __restrict__ eccp,
                                             const unsigned short* __restrict__ pe, int cap_e,
                                             const unsigned short* __restrict__ pf, int cap_f) {
    bool bf = detect_bf(x), i64 = detect_i64(ei);
    if (bf)  { if (i64) ecc_body<true,true >(q,x,nw,v,ei,fc,ew,fw,wsi,eccp,pe,cap_e,pf,cap_f);
               else     ecc_body<true,false>(q,x,nw,v,ei,fc,ew,fw,wsi,eccp,pe,cap_e,pf,cap_f); }
    else     { if (i64) ecc_body<false,true >(q,x,nw,v,ei,fc,ew,fw,wsi,eccp,pe,cap_e,pf,cap_f);
               else     ecc_body<false,false>(q,x,nw,v,ei,fc,ew,fw,wsi,eccp,pe,cap_e,pf,cap_f); }
}

// K5a: MLP layer 1. grid = 32 graphs x 8 hid-chunks = 256 blocks.
// thread t owns k-slice [8t, 8t+8): W1 loads coalesced (t*16B across wave).
template<bool BF>
__device__ __forceinline__ void mlp1_body(const void* W1, const void* b1,
                                          const void* outv, float* hbuf) {
    int g = blockIdx.x >> 3, hc = blockIdx.x & 7;
    int t = threadIdx.x;

    // flat slice -> registers (8 values)
    float fl[8];
    int fbase = NG * NCLS + g * (NB * ND) + t * 8;
    if (BF) {
        uint4 u = *(const uint4*)((const __hip_bfloat16*)outv + fbase);
        fl[0] = __uint_as_float(u.x << 16); fl[1] = __uint_as_float(u.x & 0xffff0000u);
        fl[2] = __uint_as_float(u.y << 16); fl[3] = __uint_as_float(u.y & 0xffff0000u);
        fl[4] = __uint_as_float(u.z << 16); fl[5] = __uint_as_float(u.z & 0xffff0000u);
        fl[6] = __uint_as_float(u.w << 16); fl[7] = __uint_as_float(u.w & 0xffff0000u);
    } else {
        float4 a = *(const float4*)((const float*)outv + fbase);
        float4 b = *(const float4*)((const float*)outv + fbase + 4);
        fl[0]=a.x; fl[1]=a.y; fl[2]=a.z; fl[3]=a.w;
        fl[4]=b.x; fl[5]=b.y; fl[6]=b.z; fl[7]=b.w;
    }

    float acc[32];
#pragma unroll
    for (int r = 0; r < 32; r++) acc[r] = 0.0f;
#pragma unroll 4
    for (int r = 0; r < 32; r++) {
        int hid = hc * 32 + r;
        size_t wb = (size_t)hid * (NB * ND) + t * 8;
        float wv[8];
        if (BF) {
            uint4 u = *(const uint4*)((const __hip_bfloat16*)W1 + wb);
            wv[0] = __uint_as_float(u.x << 16); wv[1] = __uint_as_float(u.x & 0xffff0000u);
            wv[2] = __uint_as_float(u.y << 16); wv[3] = __uint_as_float(u.y & 0xffff0000u);
            wv[4] = __uint_as_float(u.z << 16); wv[5] = __uint_as_float(u.z & 0xffff0000u);
            wv[6] = __uint_as_float(u.w << 16); wv[7] = __uint_as_float(u.w & 0xffff0000u);
        } else {
            float4 a = *(const float4*)((const float*)W1 + wb);
            float4 b = *(const float4*)((const float*)W1 + wb + 4);
            wv[0]=a.x; wv[1]=a.y; wv[2]=a.z; wv[3]=a.w;
            wv[4]=b.x; wv[5]=b.y; wv[6]=b.z; wv[7]=b.w;
        }
        float s = 0.0f;
#pragma unroll
        for (int j = 0; j < 8; j++) s = fmaf(wv[j], fl[j], s);
        acc[r] = s;
    }

    // transpose-reduce: red[256][33] padded
    __shared__ float red[256 * 33];
    __shared__ float pr[256];
#pragma unroll
    for (int r = 0; r < 32; r++) red[t * 33 + r] = acc[r];
    __syncthreads();
    {
        int r = t >> 3, s8 = t & 7;          // row r, slice s8 of 32 columns
        float sum = 0.0f;
#pragma unroll
        for (int i = 0; i < 32; i++) sum += red[(s8 * 32 + i) * 33 + r];
        pr[r * 8 + s8] = sum;
    }
    __syncthreads();
    if (t < 32) {
        float h = ldf<BF>(b1, hc * 32 + t);
#pragma unroll
        for (int s8 = 0; s8 < 8; s8++) h += pr[t * 8 + s8];
        hbuf[g * HIDN + hc * 32 + t] = fmaxf(h, 0.0f);
    }
}
__global__ __launch_bounds__(256) void k_mlp1(const void* __restrict__ W1,
                                              const void* __restrict__ b1,
                                              const void* __restrict__ outv,
                                              float* __restrict__ hbuf,
                                              const void* __restrict__ x) {
    if (detect_bf(x)) mlp1_body<true>(W1, b1, outv, hbuf);
    else              mlp1_body<false>(W1, b1, outv, hbuf);
}

// K5b: MLP layer 2. one block per graph; wave per output class, shuffle reduce.
template<bool BF>
__device__ __forceinline__ void mlp2_body(const void* W2, const void* b2,
                                          const float* hbuf, void* outv) {
    __shared__ float hs[HIDN];
    int g = blockIdx.x, t = threadIdx.x;
    hs[t] = hbuf[g * HIDN + t];
    __syncthreads();
    int w = t >> 6, lane = t & 63;
    for (int c = w; c < NCLS; c += 4) {
        float p = hs[lane]        * ldf<BF>(W2, c * HIDN + lane)
                + hs[lane + 64]   * ldf<BF>(W2, c * HIDN + lane + 64)
                + hs[lane + 128]  * ldf<BF>(W2, c * HIDN + lane + 128)
                + hs[lane + 192]  * ldf<BF>(W2, c * HIDN + lane + 192);
#pragma unroll
        for (int off = 32; off >= 1; off >>= 1) p += __shfl_xor(p, off);
        if (lane == 0) {
            float r = p + ldf<BF>(b2, c);
            if (BF) ((__hip_bfloat16*)outv)[g * NCLS + c] = __float2bfloat16(r);
            else    ((float*)outv)[g * NCLS + c] = r;
        }
    }
}
__global__ __launch_bounds__(256) void k_mlp2(const void* __restrict__ W2,
                                              const void* __restrict__ b2,
                                              const float* __restrict__ hbuf,
                                              void* __restrict__ outv,
                                              const void* __restrict__ x) {
    if (detect_bf(x)) mlp2_body<true>(W2, b2, hbuf, outv);
    else              mlp2_body<false>(W2, b2, hbuf, outv);
}

extern "C" void kernel_launch(void* const* d_in, const int* in_sizes, int n_in,
                              void* d_out, int out_size, void* d_ws, size_t ws_size,
                              hipStream_t stream) {
    const void* x  = d_in[0];
    const void* nw = d_in[1];
    const void* ew = d_in[2];
    const void* fw = d_in[3];
    const void* v  = d_in[4];
    const void* W1 = d_in[5];
    const void* b1 = d_in[6];
    const void* W2 = d_in[7];
    const void* b2 = d_in[8];
    const int* ei    = (const int*)d_in[9];
    const int* fc    = (const int*)d_in[10];
    const int* batch = (const int*)d_in[11];

    float*    wsf = (float*)d_ws;
    unsigned* wsu = (unsigned*)d_ws;
    int*      wsi = (int*)d_ws;
    float*    eccp = wsf + ECCP_OFF;
    float*    hbuf = wsf + HBUF_OFF;   // reuse: valid only after final flush

    int total_words = (int)(ws_size / 4);
    int avail = total_words - PERM_OFF;
    if (avail < 0) avail = 0;
    int cap_e, cap_f;
    if (avail >= 40000) { cap_e = NE; cap_f = NF; }
    else {
        int we = avail * 3 / 5;
        cap_e = we * 2; if (cap_e > NE) cap_e = NE;
        cap_f = (avail - (cap_e + 1) / 2) * 2;
        if (cap_f > NF) cap_f = NF;
        if (cap_f < 0) cap_f = 0;
    }
    unsigned short* pe = (unsigned short*)(wsi + PERM_OFF);
    unsigned short* pf = pe + (((cap_e + 1) / 2) * 2);

    k_init<<<(ZERO_WORDS + 255) / 256, 256, 0, stream>>>(batch, wsf, wsi, ei);
    k_hist32<<<EFB, 256, 0, stream>>>(ei, fc, batch, wsu);
    k_prefix32<<<1, 64, 0, stream>>>(wsu, wsi);

    for (int q = 0; q < 4; q++) {
        k_sf<<<EFB + FLB, 256, 0, stream>>>(q, q - 1, ei, fc, batch, wsi, wsu,
                                            pe, cap_e, pf, cap_f, eccp, d_out, x);
        k_ecc<<<QG * CHB, 256, 0, stream>>>(q, x, nw, v, ei, fc, ew, fw,
                                            wsi, eccp, pe, cap_e, pf, cap_f);
    }
    k_sf<<<EFB + FLB, 256, 0, stream>>>(-1, 3, ei, fc, batch, wsi, wsu,
                                        pe, cap_e, pf, cap_f, eccp, d_out, x);

    k_mlp1<<<NG * 8, 256, 0, stream>>>(W1, b1, d_out, hbuf, x);
    k_mlp2<<<NG, 256, 0, stream>>>(W2, b2, hbuf, d_out, x);
}

// Round 8
// 186.827 us; speedup vs baseline: 2.2589x; 1.1866x over previous
//
#include <hip/hip_runtime.h>
#include <hip/hip_bf16.h>

// ---- problem constants ----
constexpr int NN = 16000, NE = 48000, NF = 32000;
constexpr int ND = 64, NB = 32, NG = 32;
constexpr int HIDN = 256, NCLS = 10;
constexpr int CHB = 32;                       // chunk-blocks per graph in k_ecc
constexpr int EFB = (NE + NF + 255) / 256;    // 313 hist/scatter blocks
constexpr int PREB = (NN * ND) / 256;         // 4000 blocks in k_pre
constexpr float KLOG = 144.26950408889634f;   // 100 * log2(e)
constexpr float DLT  = 9.307710457348151f;    // (2/31) * KLOG

// ---- ws word layout (ws_size = 268 MB measured; we use ~4.6 MB) ----
constexpr int NH_OFF   = 0;                   // [NN*ND] f32 node heights (4 MB)
constexpr int ECCF_OFF = NH_OFF + NN * ND;    // [NG*NB*ND]=65536 f32 ecc
constexpr int C32_OFF  = ECCF_OFF + NG*NB*ND; // [64] u32 hist (e:0..31, f:32..63)
constexpr int CUR_OFF  = C32_OFF + 64;        // [64] u32 scatter cursors
constexpr int NOFS_OFF = CUR_OFF + 64;        // [33] i32 node boundaries
constexpr int PE_OFF   = NOFS_OFF + 34;       // u16[NE] perm (24000 words)
constexpr int PF_OFF   = PE_OFF + NE / 2;     // u16[NF] perm (16000 words)
constexpr int HB_OFF   = PF_OFF + NF / 2;     // [NG*HIDN] f32 hidden acts
constexpr int ZERO_CNT = NG * NB * ND;        // eccf zeroed in k_pre; C32/CUR via memset

__device__ __forceinline__ int clamp_node(int n) {
    return ((unsigned)n < (unsigned)NN) ? n : 0;
}
template<bool BF> __device__ __forceinline__ float ldf(const void* p, int i) {
    return BF ? __bfloat162float(((const __hip_bfloat16*)p)[i]) : ((const float*)p)[i];
}
template<bool I64> __device__ __forceinline__ int ldi(const int* p, int i) {
    return I64 ? p[2 * i] : p[i];
}

// per-block dtype self-detection (wave-uniform via ballot)
__device__ __forceinline__ bool detect_bf(const void* xp) {
    const unsigned* xw = (const unsigned*)xp;
    unsigned w = xw[threadIdx.x & 63];
    return __ballot(((w >> 23) & 0xFFu) >= 200u) != 0ull;
}
__device__ __forceinline__ bool detect_i64(const int* eip) {
    const unsigned* eiw = (const unsigned*)eip;
    unsigned o = eiw[2 * (threadIdx.x & 63) + 1];
    return __ballot(o != 0u) == 0ull;
}

// 32 bumps per thread: 4 ladder groups of 8, one exp2 each (verified R5-R7)
__device__ __forceinline__ void accum32(float h, float s, float* acc) {
    float hk = h * KLOG;
    const float kdec = __builtin_amdgcn_exp2f(-DLT);
#pragma unroll
    for (int k = 0; k < 4; k++) {
        float linc0 = (-1.0f + (float)(16 * k) / 31.0f) * KLOG;
        float t0 = fminf(fmaxf(hk - linc0, -60.0f), 126.0f);
        float e2 = __builtin_amdgcn_exp2f(t0);
#pragma unroll
        for (int j = 0; j < 8; j++) {
            acc[k*8+j] = fmaf(s, __builtin_amdgcn_rcpf(1.0f + e2), acc[k*8+j]);
            e2 *= kdec;
        }
    }
}

// K0: fused prelude — node heights nh, zero eccf, node boundaries, e/f histogram.
// grid = 4000 blocks; per wave one node row (n wave-uniform, d = lane).
template<bool BF, bool I64>
__device__ __forceinline__ void pre_body(const void* x, const void* nw, const void* v,
                                         const int* ei, const int* fc, const int* batch,
                                         float* wsf, int* wsi, unsigned* wsu) {
    int t = threadIdx.x;
    int gid = blockIdx.x * 256 + t;

    if (gid < ZERO_CNT) wsf[ECCF_OFF + gid] = 0.0f;

    if (gid < NN) {                                // node range boundaries
        int gn = ldi<I64>(batch, gid) & (NG - 1);
        int gp = (gid > 0) ? (ldi<I64>(batch, gid - 1) & (NG - 1)) : -1;
        for (int gg = gp + 1; gg <= gn; gg++) wsi[NOFS_OFF + gg] = gid;
        if (gid == NN - 1)
            for (int gg = gn + 1; gg <= NG; gg++) wsi[NOFS_OFF + gg] = NN;
    }

    {                                              // heights: gid in [0, NN*ND)
        int n = gid >> 6, d = gid & 63;
        float h = fmaf(ldf<BF>(x, n*3+2), ldf<BF>(v, 2*ND+d),
                  fmaf(ldf<BF>(x, n*3+1), ldf<BF>(v, ND+d),
                       ldf<BF>(x, n*3+0) * ldf<BF>(v, d))) * ldf<BF>(nw, n);
        wsf[NH_OFF + gid] = h;
    }

    __shared__ unsigned hb[64];
    if (blockIdx.x < EFB) {                        // histogram (block-uniform branch)
        if (t < 64) hb[t] = 0;
        __syncthreads();
        int id = blockIdx.x * 256 + t;
        if (id < NE + NF) {
            if (id < NE) atomicAdd(&hb[ldi<I64>(batch, clamp_node(ldi<I64>(ei, id))) & 31], 1u);
            else atomicAdd(&hb[32 + (ldi<I64>(batch, clamp_node(ldi<I64>(fc, id - NE))) & 31)], 1u);
        }
        __syncthreads();
        if (t < 64 && hb[t]) atomicAdd(&wsu[C32_OFF + t], hb[t]);
    }
}
__global__ __launch_bounds__(256) void k_pre(const void* __restrict__ x,
                                             const void* __restrict__ nw,
                                             const void* __restrict__ v,
                                             const int* __restrict__ ei,
                                             const int* __restrict__ fc,
                                             const int* __restrict__ batch,
                                             float* __restrict__ wsf,
                                             int* __restrict__ wsi,
                                             unsigned* __restrict__ wsu) {
    bool bf = detect_bf(x), i64 = detect_i64(ei);
    if (bf)  { if (i64) pre_body<true,true >(x,nw,v,ei,fc,batch,wsf,wsi,wsu);
               else     pre_body<true,false>(x,nw,v,ei,fc,batch,wsf,wsi,wsu); }
    else     { if (i64) pre_body<false,true >(x,nw,v,ei,fc,batch,wsf,wsi,wsu);
               else     pre_body<false,false>(x,nw,v,ei,fc,batch,wsf,wsi,wsu); }
}

// K1: single-pass scatter, all 32 graphs; bucket starts self-computed from C32
template<bool I64>
__device__ __forceinline__ void scatter_body(const int* ei, const int* fc,
                                             const int* batch, unsigned* wsu,
                                             unsigned short* pe, unsigned short* pf) {
    __shared__ unsigned cnt[64], base[64];
    __shared__ int pstart[64];
    int t = threadIdx.x;
    if (t < 64) cnt[t] = 0;
    __syncthreads();
    if (t == 0) {
        int acc = 0;
        for (int i = 0; i < 32; i++) { pstart[i] = acc; acc += (int)wsu[C32_OFF + i]; }
        acc = 0;
        for (int i = 0; i < 32; i++) { pstart[32+i] = acc; acc += (int)wsu[C32_OFF + 32 + i]; }
    }
    int id = blockIdx.x * 256 + t;
    int bin = 0; unsigned rank = 0; bool act = false;
    if (id < NE + NF) {
        if (id < NE) bin = ldi<I64>(batch, clamp_node(ldi<I64>(ei, id))) & 31;
        else         bin = 32 + (ldi<I64>(batch, clamp_node(ldi<I64>(fc, id - NE))) & 31);
        act = true;
        rank = atomicAdd(&cnt[bin], 1u);
    }
    __syncthreads();
    if (t < 64) base[t] = cnt[t] ? atomicAdd(&wsu[CUR_OFF + t], cnt[t]) : 0u;
    __syncthreads();
    if (act) {
        int pos = pstart[bin] + (int)(base[bin] + rank);
        if (bin < 32) { if (pos >= 0 && pos < NE) pe[pos] = (unsigned short)id; }
        else          { if (pos >= 0 && pos < NF) pf[pos] = (unsigned short)(id - NE); }
    }
}
__global__ __launch_bounds__(256) void k_scatter(const int* __restrict__ ei,
                                                 const int* __restrict__ fc,
                                                 const int* __restrict__ batch,
                                                 unsigned* __restrict__ wsu,
                                                 unsigned short* __restrict__ pe,
                                                 unsigned short* __restrict__ pf) {
    if (detect_i64(ei)) scatter_body<true>(ei, fc, batch, wsu, pe, pf);
    else                scatter_body<false>(ei, fc, batch, wsu, pe, pf);
}

// K2: single-pass ecc, all graphs. grid = NG*CHB = 1024 blocks; wave-stream per
// element, lane = dir; heights via coalesced nh row gathers.
template<bool BF, bool I64>
__device__ __forceinline__ void ecc_body(const int* ei, const int* fc,
                                         const void* ew, const void* fw,
                                         const float* nh, const int* wsi,
                                         const unsigned* wsu, float* eccf,
                                         const unsigned short* pe,
                                         const unsigned short* pf) {
    int t = threadIdx.x;
    int d = t & 63;
    int w = __builtin_amdgcn_readfirstlane(t) >> 6;
    int g  = blockIdx.x >> 5;                 // / CHB
    int cb = blockIdx.x & (CHB - 1);
    int sid = cb * 4 + w;
    const int S = CHB * 4;                    // 128 streams per graph

    __shared__ int sofs[4];                   // estart, ecnt, fstart, fcnt
    if (t == 0) {
        int ea = 0, fa = 0;
        for (int i = 0; i < 32; i++) {
            if (i < g) { ea += (int)wsu[C32_OFF + i]; fa += (int)wsu[C32_OFF + 32 + i]; }
        }
        sofs[0] = ea; sofs[1] = (int)wsu[C32_OFF + g];
        sofs[2] = fa; sofs[3] = (int)wsu[C32_OFF + 32 + g];
    }
    __syncthreads();

    float acc[32];
#pragma unroll
    for (int j = 0; j < 32; j++) acc[j] = 0.0f;

    // nodes (+1)
    int ns = wsi[NOFS_OFF + g], nend = wsi[NOFS_OFF + g + 1];
    int i = ns + sid;
    for (; i + S < nend; i += 2 * S) {
        float h1 = nh[i * ND + d];
        float h2 = nh[(i + S) * ND + d];
        accum32(h1, 1.0f, acc);
        accum32(h2, 1.0f, acc);
    }
    if (i < nend) accum32(nh[i * ND + d], 1.0f, acc);

    // edges (-1)
    int es = sofs[0], ee = min(sofs[0] + sofs[1], NE);
    i = es + sid;
    for (; i + S < ee; i += 2 * S) {
        int e1 = pe[i], e2 = pe[i + S];
        int a1 = clamp_node(ldi<I64>(ei, e1)), b1 = clamp_node(ldi<I64>(ei, NE + e1));
        int a2 = clamp_node(ldi<I64>(ei, e2)), b2 = clamp_node(ldi<I64>(ei, NE + e2));
        float h1 = fmaxf(nh[a1 * ND + d], nh[b1 * ND + d]) * ldf<BF>(ew, e1);
        float h2 = fmaxf(nh[a2 * ND + d], nh[b2 * ND + d]) * ldf<BF>(ew, e2);
        accum32(h1, -1.0f, acc);
        accum32(h2, -1.0f, acc);
    }
    if (i < ee) {
        int e = pe[i];
        int a = clamp_node(ldi<I64>(ei, e)), b = clamp_node(ldi<I64>(ei, NE + e));
        accum32(fmaxf(nh[a * ND + d], nh[b * ND + d]) * ldf<BF>(ew, e), -1.0f, acc);
    }

    // faces (+1)
    int fs0 = sofs[2], fe = min(sofs[2] + sofs[3], NF);
    i = fs0 + sid;
    for (; i + S < fe; i += 2 * S) {
        int f1 = pf[i], f2 = pf[i + S];
        int a1 = clamp_node(ldi<I64>(fc, f1)), b1 = clamp_node(ldi<I64>(fc, NF + f1));
        int c1 = clamp_node(ldi<I64>(fc, 2*NF + f1));
        int a2 = clamp_node(ldi<I64>(fc, f2)), b2 = clamp_node(ldi<I64>(fc, NF + f2));
        int c2 = clamp_node(ldi<I64>(fc, 2*NF + f2));
        float h1 = fmaxf(fmaxf(nh[a1*ND+d], nh[b1*ND+d]), nh[c1*ND+d]) * ldf<BF>(fw, f1);
        float h2 = fmaxf(fmaxf(nh[a2*ND+d], nh[b2*ND+d]), nh[c2*ND+d]) * ldf<BF>(fw, f2);
        accum32(h1, 1.0f, acc);
        accum32(h2, 1.0f, acc);
    }
    if (i < fe) {
        int f = pf[i];
        int a = clamp_node(ldi<I64>(fc, f)), b = clamp_node(ldi<I64>(fc, NF + f));
        int c = clamp_node(ldi<I64>(fc, 2*NF + f));
        accum32(fmaxf(fmaxf(nh[a*ND+d], nh[b*ND+d]), nh[c*ND+d]) * ldf<BF>(fw, f), 1.0f, acc);
    }

    // block reduction: 4 waves -> 1, then 2048 atomics/block
    __shared__ float red[4][NB * ND];
#pragma unroll
    for (int j = 0; j < 32; j++) red[w][j * 64 + d] = acc[j];
    __syncthreads();
    for (int jj = t; jj < NB * ND; jj += 256) {
        float sum = red[0][jj] + red[1][jj] + red[2][jj] + red[3][jj];
        atomicAdd(&eccf[g * (NB * ND) + jj], sum);
    }
}
__global__ __launch_bounds__(256) void k_ecc(const int* __restrict__ ei,
                                             const int* __restrict__ fc,
                                             const void* __restrict__ ew,
                                             const void* __restrict__ fw,
                                             const float* __restrict__ nh,
                                             const int* __restrict__ wsi,
                                             const unsigned* __restrict__ wsu,
                                             float* __restrict__ eccf,
                                             const unsigned short* __restrict__ pe,
                                             const unsigned short* __restrict__ pf,
                                             const void* __restrict__ x) {
    bool bf = detect_bf(x), i64 = detect_i64(ei);
    if (bf)  { if (i64) ecc_body<true,true >(ei,fc,ew,fw,nh,wsi,wsu,eccf,pe,pf);
               else     ecc_body<true,false>(ei,fc,ew,fw,nh,wsi,wsu,eccf,pe,pf); }
    else     { if (i64) ecc_body<false,true >(ei,fc,ew,fw,nh,wsi,wsu,eccf,pe,pf);
               else     ecc_body<false,false>(ei,fc,ew,fw,nh,wsi,wsu,eccf,pe,pf); }
}

// K3: MLP layer 1 + fused flat-output flush. grid = 32 graphs x 8 hid-chunks.
template<bool BF>
__device__ __forceinline__ void mlp1_body(const void* W1, const void* b1,
                                          const float* eccf, float* hbuf,
                                          void* outv) {
    int g = blockIdx.x >> 3, hc = blockIdx.x & 7;
    int t = threadIdx.x;

    const float4* fp = (const float4*)(eccf + g * (NB * ND) + t * 8);
    float4 fa = fp[0], fb = fp[1];
    float fl[8] = {fa.x, fa.y, fa.z, fa.w, fb.x, fb.y, fb.z, fb.w};

    if (hc == 0) {                              // flush flat output (once per graph)
        int ob = NG * NCLS + g * (NB * ND) + t * 8;
        if (BF) {
#pragma unroll
            for (int j = 0; j < 8; j++)
                ((__hip_bfloat16*)outv)[ob + j] = __float2bfloat16(fl[j]);
        } else {
            ((float4*)((float*)outv + ob))[0] = fa;
            ((float4*)((float*)outv + ob))[1] = fb;
        }
    }

    float acc[32];
#pragma unroll
    for (int r = 0; r < 32; r++) acc[r] = 0.0f;
#pragma unroll 4
    for (int r = 0; r < 32; r++) {
        int hid = hc * 32 + r;
        size_t wb = (size_t)hid * (NB * ND) + t * 8;
        float wv[8];
        if (BF) {
            uint4 u = *(const uint4*)((const __hip_bfloat16*)W1 + wb);
            wv[0] = __uint_as_float(u.x << 16); wv[1] = __uint_as_float(u.x & 0xffff0000u);
            wv[2] = __uint_as_float(u.y << 16); wv[3] = __uint_as_float(u.y & 0xffff0000u);
            wv[4] = __uint_as_float(u.z << 16); wv[5] = __uint_as_float(u.z & 0xffff0000u);
            wv[6] = __uint_as_float(u.w << 16); wv[7] = __uint_as_float(u.w & 0xffff0000u);
        } else {
            float4 a = *(const float4*)((const float*)W1 + wb);
            float4 b = *(const float4*)((const float*)W1 + wb + 4);
            wv[0]=a.x; wv[1]=a.y; wv[2]=a.z; wv[3]=a.w;
            wv[4]=b.x; wv[5]=b.y; wv[6]=b.z; wv[7]=b.w;
        }
        float s = 0.0f;
#pragma unroll
        for (int j = 0; j < 8; j++) s = fmaf(wv[j], fl[j], s);
        acc[r] = s;
    }

    __shared__ float red[256 * 33];
    __shared__ float pr[256];
#pragma unroll
    for (int r = 0; r < 32; r++) red[t * 33 + r] = acc[r];
    __syncthreads();
    {
        int r = t >> 3, s8 = t & 7;
        float sum = 0.0f;
#pragma unroll
        for (int i = 0; i < 32; i++) sum += red[(s8 * 32 + i) * 33 + r];
        pr[r * 8 + s8] = sum;
    }
    __syncthreads();
    if (t < 32) {
        float h = ldf<BF>(b1, hc * 32 + t);
#pragma unroll
        for (int s8 = 0; s8 < 8; s8++) h += pr[t * 8 + s8];
        hbuf[g * HIDN + hc * 32 + t] = fmaxf(h, 0.0f);
    }
}
__global__ __launch_bounds__(256) void k_mlp1(const void* __restrict__ W1,
                                              const void* __restrict__ b1,
                                              const float* __restrict__ eccf,
                                              float* __restrict__ hbuf,
                                              void* __restrict__ outv,
                                              const void* __restrict__ x) {
    if (detect_bf(x)) mlp1_body<true>(W1, b1, eccf, hbuf, outv);
    else              mlp1_body<false>(W1, b1, eccf, hbuf, outv);
}

// K4: MLP layer 2. one block per graph; wave per class, shuffle reduce.
template<bool BF>
__device__ __forceinline__ void mlp2_body(const void* W2, const void* b2,
                                          const float* hbuf, void* outv) {
    __shared__ float hs[HIDN];
    int g = blockIdx.x, t = threadIdx.x;
    hs[t] = hbuf[g * HIDN + t];
    __syncthreads();
    int w = t >> 6, lane = t & 63;
    for (int c = w; c < NCLS; c += 4) {
        float p = hs[lane]        * ldf<BF>(W2, c * HIDN + lane)
                + hs[lane + 64]   * ldf<BF>(W2, c * HIDN + lane + 64)
                + hs[lane + 128]  * ldf<BF>(W2, c * HIDN + lane + 128)
                + hs[lane + 192]  * ldf<BF>(W2, c * HIDN + lane + 192);
#pragma unroll
        for (int off = 32; off >= 1; off >>= 1) p += __shfl_xor(p, off);
        if (lane == 0) {
            float r = p + ldf<BF>(b2, c);
            if (BF) ((__hip_bfloat16*)outv)[g * NCLS + c] = __float2bfloat16(r);
            else    ((float*)outv)[g * NCLS + c] = r;
        }
    }
}
__global__ __launch_bounds__(256) void k_mlp2(const void* __restrict__ W2,
                                              const void* __restrict__ b2,
                                              const float* __restrict__ hbuf,
                                              void* __restrict__ outv,
                                              const void* __restrict__ x) {
    if (detect_bf(x)) mlp2_body<true>(W2, b2, hbuf, outv);
    else              mlp2_body<false>(W2, b2, hbuf, outv);
}

extern "C" void kernel_launch(void* const* d_in, const int* in_sizes, int n_in,
                              void* d_out, int out_size, void* d_ws, size_t ws_size,
                              hipStream_t stream) {
    const void* x  = d_in[0];
    const void* nw = d_in[1];
    const void* ew = d_in[2];
    const void* fw = d_in[3];
    const void* v  = d_in[4];
    const void* W1 = d_in[5];
    const void* b1 = d_in[6];
    const void* W2 = d_in[7];
    const void* b2 = d_in[8];
    const int* ei    = (const int*)d_in[9];
    const int* fc    = (const int*)d_in[10];
    const int* batch = (const int*)d_in[11];

    float*    wsf = (float*)d_ws;
    unsigned* wsu = (unsigned*)d_ws;
    int*      wsi = (int*)d_ws;
    float*    nh   = wsf + NH_OFF;
    float*    eccf = wsf + ECCF_OFF;
    float*    hbuf = wsf + HB_OFF;
    unsigned short* pe = (unsigned short*)(wsi + PE_OFF);
    unsigned short* pf = (unsigned short*)(wsi + PF_OFF);

    // zero the 128-word hist+cursor meta region (stream-ordered, capture-safe)
    hipMemsetAsync((char*)d_ws + (size_t)C32_OFF * 4, 0, 128 * 4, stream);

    k_pre<<<PREB, 256, 0, stream>>>(x, nw, v, ei, fc, batch, wsf, wsi, wsu);
    k_scatter<<<EFB, 256, 0, stream>>>(ei, fc, batch, wsu, pe, pf);
    k_ecc<<<NG * CHB, 256, 0, stream>>>(ei, fc, ew, fw, nh, wsi, wsu, eccf, pe, pf, x);
    k_mlp1<<<NG * 8, 256, 0, stream>>>(W1, b1, eccf, hbuf, d_out, x);
    k_mlp2<<<NG, 256, 0, stream>>>(W2, b2, hbuf, d_out, x);
}

// Round 9
// 147.477 us; speedup vs baseline: 2.8616x; 1.2668x over previous
//
#include <hip/hip_runtime.h>
#include <hip/hip_bf16.h>

// ---- problem constants ----
constexpr int NN = 16000, NE = 48000, NF = 32000;
constexpr int ND = 64, NB = 32, NG = 32;
constexpr int HIDN = 256, NCLS = 10;
constexpr int CHB = 32;                       // chunk-blocks per graph in k_ecc
constexpr int EFB = (NE + NF + 255) / 256;    // 313 hist/scatter blocks
constexpr int PREB = (NN * ND) / 256;         // 4000 blocks in k_pre
constexpr float KLOG = 144.26950408889634f;   // 100 * log2(e)
constexpr float DLT  = 9.307710457348151f;    // (2/31) * KLOG

// ---- ws word layout (ws_size = 268 MB measured; we use ~4.6 MB) ----
constexpr int NH_OFF   = 0;                   // [NN*ND] f32 node heights (4 MB)
constexpr int ECCF_OFF = NH_OFF + NN * ND;    // [NG*NB*ND]=65536 f32 ecc
constexpr int C32_OFF  = ECCF_OFF + NG*NB*ND; // [64] u32 hist (e:0..31, f:32..63)
constexpr int CUR_OFF  = C32_OFF + 64;        // [64] u32 scatter cursors
constexpr int NOFS_OFF = CUR_OFF + 64;        // [33] i32 node boundaries
constexpr int PE_OFF   = NOFS_OFF + 34;       // u16[NE] perm (24000 words)
constexpr int PF_OFF   = PE_OFF + NE / 2;     // u16[NF] perm (16000 words)
constexpr int HB_OFF   = PF_OFF + NF / 2;     // [NG*HIDN] f32 hidden acts
constexpr int ZERO_CNT = NG * NB * ND;        // eccf zeroed in k_pre

__device__ __forceinline__ int clamp_node(int n) {
    return ((unsigned)n < (unsigned)NN) ? n : 0;
}
template<bool BF> __device__ __forceinline__ float ldf(const void* p, int i) {
    return BF ? __bfloat162float(((const __hip_bfloat16*)p)[i]) : ((const float*)p)[i];
}
template<bool I64> __device__ __forceinline__ int ldi(const int* p, int i) {
    return I64 ? p[2 * i] : p[i];
}

// per-block dtype self-detection (wave-uniform via ballot)
__device__ __forceinline__ bool detect_bf(const void* xp) {
    const unsigned* xw = (const unsigned*)xp;
    unsigned w = xw[threadIdx.x & 63];
    return __ballot(((w >> 23) & 0xFFu) >= 200u) != 0ull;
}
__device__ __forceinline__ bool detect_i64(const int* eip) {
    const unsigned* eiw = (const unsigned*)eip;
    unsigned o = eiw[2 * (threadIdx.x & 63) + 1];
    return __ballot(o != 0u) == 0ull;
}

// 32 bumps per thread: 4 ladder groups of 8, one exp2 each (verified R5-R8)
__device__ __forceinline__ void accum32(float h, float s, float* acc) {
    float hk = h * KLOG;
    const float kdec = __builtin_amdgcn_exp2f(-DLT);
#pragma unroll
    for (int k = 0; k < 4; k++) {
        float linc0 = (-1.0f + (float)(16 * k) / 31.0f) * KLOG;
        float t0 = fminf(fmaxf(hk - linc0, -60.0f), 126.0f);
        float e2 = __builtin_amdgcn_exp2f(t0);
#pragma unroll
        for (int j = 0; j < 8; j++) {
            acc[k*8+j] = fmaf(s, __builtin_amdgcn_rcpf(1.0f + e2), acc[k*8+j]);
            e2 *= kdec;
        }
    }
}

// K0: fused prelude — node heights nh, zero eccf, node boundaries, e/f histogram.
template<bool BF, bool I64>
__device__ __forceinline__ void pre_body(const void* x, const void* nw, const void* v,
                                         const int* ei, const int* fc, const int* batch,
                                         float* wsf, int* wsi, unsigned* wsu,
                                         unsigned* hb) {
    int t = threadIdx.x;
    int gid = blockIdx.x * 256 + t;

    if (gid < ZERO_CNT) wsf[ECCF_OFF + gid] = 0.0f;

    if (gid < NN) {                                // node range boundaries
        int gn = ldi<I64>(batch, gid) & (NG - 1);
        int gp = (gid > 0) ? (ldi<I64>(batch, gid - 1) & (NG - 1)) : -1;
        for (int gg = gp + 1; gg <= gn; gg++) wsi[NOFS_OFF + gg] = gid;
        if (gid == NN - 1)
            for (int gg = gn + 1; gg <= NG; gg++) wsi[NOFS_OFF + gg] = NN;
    }

    {                                              // heights: gid in [0, NN*ND)
        int n = gid >> 6, d = gid & 63;
        float h = fmaf(ldf<BF>(x, n*3+2), ldf<BF>(v, 2*ND+d),
                  fmaf(ldf<BF>(x, n*3+1), ldf<BF>(v, ND+d),
                       ldf<BF>(x, n*3+0) * ldf<BF>(v, d))) * ldf<BF>(nw, n);
        wsf[NH_OFF + gid] = h;
    }

    if (blockIdx.x < EFB) {                        // histogram (block-uniform branch)
        if (t < 64) hb[t] = 0;
        __syncthreads();
        int id = blockIdx.x * 256 + t;
        if (id < NE + NF) {
            if (id < NE) atomicAdd(&hb[ldi<I64>(batch, clamp_node(ldi<I64>(ei, id))) & 31], 1u);
            else atomicAdd(&hb[32 + (ldi<I64>(batch, clamp_node(ldi<I64>(fc, id - NE))) & 31)], 1u);
        }
        __syncthreads();
        if (t < 64 && hb[t]) atomicAdd(&wsu[C32_OFF + t], hb[t]);
    }
}
__global__ __launch_bounds__(256) void k_pre(const void* __restrict__ x,
                                             const void* __restrict__ nw,
                                             const void* __restrict__ v,
                                             const int* __restrict__ ei,
                                             const int* __restrict__ fc,
                                             const int* __restrict__ batch,
                                             float* __restrict__ wsf,
                                             int* __restrict__ wsi,
                                             unsigned* __restrict__ wsu) {
    __shared__ unsigned hb[64];                    // single alloc, shared by instantiations
    bool bf = detect_bf(x), i64 = detect_i64(ei);
    if (bf)  { if (i64) pre_body<true,true >(x,nw,v,ei,fc,batch,wsf,wsi,wsu,hb);
               else     pre_body<true,false>(x,nw,v,ei,fc,batch,wsf,wsi,wsu,hb); }
    else     { if (i64) pre_body<false,true >(x,nw,v,ei,fc,batch,wsf,wsi,wsu,hb);
               else     pre_body<false,false>(x,nw,v,ei,fc,batch,wsf,wsi,wsu,hb); }
}

// K1: single-pass scatter, all 32 graphs
template<bool I64>
__device__ __forceinline__ void scatter_body(const int* ei, const int* fc,
                                             const int* batch, unsigned* wsu,
                                             unsigned short* pe, unsigned short* pf,
                                             unsigned* cnt, unsigned* base, int* pstart) {
    int t = threadIdx.x;
    if (t < 64) cnt[t] = 0;
    __syncthreads();
    if (t == 0) {
        int acc = 0;
        for (int i = 0; i < 32; i++) { pstart[i] = acc; acc += (int)wsu[C32_OFF + i]; }
        acc = 0;
        for (int i = 0; i < 32; i++) { pstart[32+i] = acc; acc += (int)wsu[C32_OFF + 32 + i]; }
    }
    int id = blockIdx.x * 256 + t;
    int bin = 0; unsigned rank = 0; bool act = false;
    if (id < NE + NF) {
        if (id < NE) bin = ldi<I64>(batch, clamp_node(ldi<I64>(ei, id))) & 31;
        else         bin = 32 + (ldi<I64>(batch, clamp_node(ldi<I64>(fc, id - NE))) & 31);
        act = true;
        rank = atomicAdd(&cnt[bin], 1u);
    }
    __syncthreads();
    if (t < 64) base[t] = cnt[t] ? atomicAdd(&wsu[CUR_OFF + t], cnt[t]) : 0u;
    __syncthreads();
    if (act) {
        int pos = pstart[bin] + (int)(base[bin] + rank);
        if (bin < 32) { if (pos >= 0 && pos < NE) pe[pos] = (unsigned short)id; }
        else          { if (pos >= 0 && pos < NF) pf[pos] = (unsigned short)(id - NE); }
    }
}
__global__ __launch_bounds__(256) void k_scatter(const int* __restrict__ ei,
                                                 const int* __restrict__ fc,
                                                 const int* __restrict__ batch,
                                                 unsigned* __restrict__ wsu,
                                                 unsigned short* __restrict__ pe,
                                                 unsigned short* __restrict__ pf) {
    __shared__ unsigned cnt[64], base[64];
    __shared__ int pstart[64];
    if (detect_i64(ei)) scatter_body<true>(ei, fc, batch, wsu, pe, pf, cnt, base, pstart);
    else                scatter_body<false>(ei, fc, batch, wsu, pe, pf, cnt, base, pstart);
}

// K2: single-pass ecc. grid = NG*CHB = 1024 blocks; wave-stream per element.
template<bool BF, bool I64>
__device__ __forceinline__ void ecc_body(const int* ei, const int* fc,
                                         const void* ew, const void* fw,
                                         const float* nh, const int* wsi,
                                         const unsigned* wsu, float* eccf,
                                         const unsigned short* pe,
                                         const unsigned short* pf,
                                         float (*red)[NB * ND], int* sofs) {
    int t = threadIdx.x;
    int d = t & 63;
    int w = __builtin_amdgcn_readfirstlane(t) >> 6;
    int g  = blockIdx.x >> 5;                 // / CHB
    int cb = blockIdx.x & (CHB - 1);
    int sid = cb * 4 + w;
    const int S = CHB * 4;                    // 128 streams per graph

    if (t == 0) {
        int ea = 0, fa = 0;
        for (int i = 0; i < 32; i++) {
            if (i < g) { ea += (int)wsu[C32_OFF + i]; fa += (int)wsu[C32_OFF + 32 + i]; }
        }
        sofs[0] = ea; sofs[1] = (int)wsu[C32_OFF + g];
        sofs[2] = fa; sofs[3] = (int)wsu[C32_OFF + 32 + g];
    }
    __syncthreads();

    float acc[32];
#pragma unroll
    for (int j = 0; j < 32; j++) acc[j] = 0.0f;

    // nodes (+1)
    int ns = wsi[NOFS_OFF + g], nend = wsi[NOFS_OFF + g + 1];
    int i = ns + sid;
    for (; i + S < nend; i += 2 * S) {
        float h1 = nh[i * ND + d];
        float h2 = nh[(i + S) * ND + d];
        accum32(h1, 1.0f, acc);
        accum32(h2, 1.0f, acc);
    }
    if (i < nend) accum32(nh[i * ND + d], 1.0f, acc);

    // edges (-1)
    int es = sofs[0], ee = min(sofs[0] + sofs[1], NE);
    i = es + sid;
    for (; i + S < ee; i += 2 * S) {
        int e1 = pe[i], e2 = pe[i + S];
        int a1 = clamp_node(ldi<I64>(ei, e1)), b1 = clamp_node(ldi<I64>(ei, NE + e1));
        int a2 = clamp_node(ldi<I64>(ei, e2)), b2 = clamp_node(ldi<I64>(ei, NE + e2));
        float h1 = fmaxf(nh[a1 * ND + d], nh[b1 * ND + d]) * ldf<BF>(ew, e1);
        float h2 = fmaxf(nh[a2 * ND + d], nh[b2 * ND + d]) * ldf<BF>(ew, e2);
        accum32(h1, -1.0f, acc);
        accum32(h2, -1.0f, acc);
    }
    if (i < ee) {
        int e = pe[i];
        int a = clamp_node(ldi<I64>(ei, e)), b = clamp_node(ldi<I64>(ei, NE + e));
        accum32(fmaxf(nh[a * ND + d], nh[b * ND + d]) * ldf<BF>(ew, e), -1.0f, acc);
    }

    // faces (+1)
    int fs0 = sofs[2], fe = min(sofs[2] + sofs[3], NF);
    i = fs0 + sid;
    for (; i + S < fe; i += 2 * S) {
        int f1 = pf[i], f2 = pf[i + S];
        int a1 = clamp_node(ldi<I64>(fc, f1)), b1 = clamp_node(ldi<I64>(fc, NF + f1));
        int c1 = clamp_node(ldi<I64>(fc, 2*NF + f1));
        int a2 = clamp_node(ldi<I64>(fc, f2)), b2 = clamp_node(ldi<I64>(fc, NF + f2));
        int c2 = clamp_node(ldi<I64>(fc, 2*NF + f2));
        float h1 = fmaxf(fmaxf(nh[a1*ND+d], nh[b1*ND+d]), nh[c1*ND+d]) * ldf<BF>(fw, f1);
        float h2 = fmaxf(fmaxf(nh[a2*ND+d], nh[b2*ND+d]), nh[c2*ND+d]) * ldf<BF>(fw, f2);
        accum32(h1, 1.0f, acc);
        accum32(h2, 1.0f, acc);
    }
    if (i < fe) {
        int f = pf[i];
        int a = clamp_node(ldi<I64>(fc, f)), b = clamp_node(ldi<I64>(fc, NF + f));
        int c = clamp_node(ldi<I64>(fc, 2*NF + f));
        accum32(fmaxf(fmaxf(nh[a*ND+d], nh[b*ND+d]), nh[c*ND+d]) * ldf<BF>(fw, f), 1.0f, acc);
    }

    // block reduction: 4 waves -> 1, then 2048 atomics/block
#pragma unroll
    for (int j = 0; j < 32; j++) red[w][j * 64 + d] = acc[j];
    __syncthreads();
    for (int jj = t; jj < NB * ND; jj += 256) {
        float sum = red[0][jj] + red[1][jj] + red[2][jj] + red[3][jj];
        atomicAdd(&eccf[g * (NB * ND) + jj], sum);
    }
}
__global__ __launch_bounds__(256, 4) void k_ecc(const int* __restrict__ ei,
                                                const int* __restrict__ fc,
                                                const void* __restrict__ ew,
                                                const void* __restrict__ fw,
                                                const float* __restrict__ nh,
                                                const int* __restrict__ wsi,
                                                const unsigned* __restrict__ wsu,
                                                float* __restrict__ eccf,
                                                const unsigned short* __restrict__ pe,
                                                const unsigned short* __restrict__ pf,
                                                const void* __restrict__ x) {
    __shared__ float red[4][NB * ND];              // ONE 32 KB alloc for all instantiations
    __shared__ int sofs[4];
    bool bf = detect_bf(x), i64 = detect_i64(ei);
    if (bf)  { if (i64) ecc_body<true,true >(ei,fc,ew,fw,nh,wsi,wsu,eccf,pe,pf,red,sofs);
               else     ecc_body<true,false>(ei,fc,ew,fw,nh,wsi,wsu,eccf,pe,pf,red,sofs); }
    else     { if (i64) ecc_body<false,true >(ei,fc,ew,fw,nh,wsi,wsu,eccf,pe,pf,red,sofs);
               else     ecc_body<false,false>(ei,fc,ew,fw,nh,wsi,wsu,eccf,pe,pf,red,sofs); }
}

// K3: MLP layer 1 + fused flat-output flush. grid = 32 graphs x 8 hid-chunks.
template<bool BF>
__device__ __forceinline__ void mlp1_body(const void* W1, const void* b1,
                                          const float* eccf, float* hbuf,
                                          void* outv, float* red, float* pr) {
    int g = blockIdx.x >> 3, hc = blockIdx.x & 7;
    int t = threadIdx.x;

    const float4* fp = (const float4*)(eccf + g * (NB * ND) + t * 8);
    float4 fa = fp[0], fb = fp[1];
    float fl[8] = {fa.x, fa.y, fa.z, fa.w, fb.x, fb.y, fb.z, fb.w};

    if (hc == 0) {                              // flush flat output (once per graph)
        int ob = NG * NCLS + g * (NB * ND) + t * 8;
        if (BF) {
#pragma unroll
            for (int j = 0; j < 8; j++)
                ((__hip_bfloat16*)outv)[ob + j] = __float2bfloat16(fl[j]);
        } else {
            ((float4*)((float*)outv + ob))[0] = fa;
            ((float4*)((float*)outv + ob))[1] = fb;
        }
    }

    float acc[32];
#pragma unroll
    for (int r = 0; r < 32; r++) acc[r] = 0.0f;
#pragma unroll 4
    for (int r = 0; r < 32; r++) {
        int hid = hc * 32 + r;
        size_t wb = (size_t)hid * (NB * ND) + t * 8;
        float wv[8];
        if (BF) {
            uint4 u = *(const uint4*)((const __hip_bfloat16*)W1 + wb);
            wv[0] = __uint_as_float(u.x << 16); wv[1] = __uint_as_float(u.x & 0xffff0000u);
            wv[2] = __uint_as_float(u.y << 16); wv[3] = __uint_as_float(u.y & 0xffff0000u);
            wv[4] = __uint_as_float(u.z << 16); wv[5] = __uint_as_float(u.z & 0xffff0000u);
            wv[6] = __uint_as_float(u.w << 16); wv[7] = __uint_as_float(u.w & 0xffff0000u);
        } else {
            float4 a = *(const float4*)((const float*)W1 + wb);
            float4 b = *(const float4*)((const float*)W1 + wb + 4);
            wv[0]=a.x; wv[1]=a.y; wv[2]=a.z; wv[3]=a.w;
            wv[4]=b.x; wv[5]=b.y; wv[6]=b.z; wv[7]=b.w;
        }
        float s = 0.0f;
#pragma unroll
        for (int j = 0; j < 8; j++) s = fmaf(wv[j], fl[j], s);
        acc[r] = s;
    }

#pragma unroll
    for (int r = 0; r < 32; r++) red[t * 33 + r] = acc[r];
    __syncthreads();
    {
        int r = t >> 3, s8 = t & 7;
        float sum = 0.0f;
#pragma unroll
        for (int i = 0; i < 32; i++) sum += red[(s8 * 32 + i) * 33 + r];
        pr[r * 8 + s8] = sum;
    }
    __syncthreads();
    if (t < 32) {
        float h = ldf<BF>(b1, hc * 32 + t);
#pragma unroll
        for (int s8 = 0; s8 < 8; s8++) h += pr[t * 8 + s8];
        hbuf[g * HIDN + hc * 32 + t] = fmaxf(h, 0.0f);
    }
}
__global__ __launch_bounds__(256) void k_mlp1(const void* __restrict__ W1,
                                              const void* __restrict__ b1,
                                              const float* __restrict__ eccf,
                                              float* __restrict__ hbuf,
                                              void* __restrict__ outv,
                                              const void* __restrict__ x) {
    __shared__ float red[256 * 33];
    __shared__ float pr[256];
    if (detect_bf(x)) mlp1_body<true>(W1, b1, eccf, hbuf, outv, red, pr);
    else              mlp1_body<false>(W1, b1, eccf, hbuf, outv, red, pr);
}

// K4: MLP layer 2. one block per graph; wave per class, shuffle reduce.
template<bool BF>
__device__ __forceinline__ void mlp2_body(const void* W2, const void* b2,
                                          const float* hbuf, void* outv, float* hs) {
    int g = blockIdx.x, t = threadIdx.x;
    hs[t] = hbuf[g * HIDN + t];
    __syncthreads();
    int w = t >> 6, lane = t & 63;
    for (int c = w; c < NCLS; c += 4) {
        float p = hs[lane]        * ldf<BF>(W2, c * HIDN + lane)
                + hs[lane + 64]   * ldf<BF>(W2, c * HIDN + lane + 64)
                + hs[lane + 128]  * ldf<BF>(W2, c * HIDN + lane + 128)
                + hs[lane + 192]  * ldf<BF>(W2, c * HIDN + lane + 192);
#pragma unroll
        for (int off = 32; off >= 1; off >>= 1) p += __shfl_xor(p, off);
        if (lane == 0) {
            float r = p + ldf<BF>(b2, c);
            if (BF) ((__hip_bfloat16*)outv)[g * NCLS + c] = __float2bfloat16(r);
            else    ((float*)outv)[g * NCLS + c] = r;
        }
    }
}
__global__ __launch_bounds__(256) void k_mlp2(const void* __restrict__ W2,
                                              const void* __restrict__ b2,
                                              const float* __restrict__ hbuf,
                                              void* __restrict__ outv,
                                              const void* __restrict__ x) {
    __shared__ float hs[HIDN];
    if (detect_bf(x)) mlp2_body<true>(W2, b2, hbuf, outv, hs);
    else              mlp2_body<false>(W2, b2, hbuf, outv, hs);
}

extern "C" void kernel_launch(void* const* d_in, const int* in_sizes, int n_in,
                              void* d_out, int out_size, void* d_ws, size_t ws_size,
                              hipStream_t stream) {
    const void* x  = d_in[0];
    const void* nw = d_in[1];
    const void* ew = d_in[2];
    const void* fw = d_in[3];
    const void* v  = d_in[4];
    const void* W1 = d_in[5];
    const void* b1 = d_in[6];
    const void* W2 = d_in[7];
    const void* b2 = d_in[8];
    const int* ei    = (const int*)d_in[9];
    const int* fc    = (const int*)d_in[10];
    const int* batch = (const int*)d_in[11];

    float*    wsf = (float*)d_ws;
    unsigned* wsu = (unsigned*)d_ws;
    int*      wsi = (int*)d_ws;
    float*    nh   = wsf + NH_OFF;
    float*    eccf = wsf + ECCF_OFF;
    float*    hbuf = wsf + HB_OFF;
    unsigned short* pe = (unsigned short*)(wsi + PE_OFF);
    unsigned short* pf = (unsigned short*)(wsi + PF_OFF);

    hipMemsetAsync((char*)d_ws + (size_t)C32_OFF * 4, 0, 128 * 4, stream);

    k_pre<<<PREB, 256, 0, stream>>>(x, nw, v, ei, fc, batch, wsf, wsi, wsu);
    k_scatter<<<EFB, 256, 0, stream>>>(ei, fc, batch, wsu, pe, pf);
    k_ecc<<<NG * CHB, 256, 0, stream>>>(ei, fc, ew, fw, nh, wsi, wsu, eccf, pe, pf, x);
    k_mlp1<<<NG * 8, 256, 0, stream>>>(W1, b1, eccf, hbuf, d_out, x);
    k_mlp2<<<NG, 256, 0, stream>>>(W2, b2, hbuf, d_out, x);
}